// Round 15
// baseline (372.640 us; speedup 1.0000x reference)
//
#include <hip/hip_runtime.h>
#include <hip/hip_fp16.h>
#include <math.h>

#define NB 16
#define PI2 6.28318530717958647692f

struct Levels {
  int n[6], kn[6];
  int zt_off[6];   // half elements
  int zxy_off[6];  // float elements
  int z6_off[6];   // half elements
  int u_off[6];    // half elements
  int gstart[7];
  float scale[6];
};
struct WArgs {
  const float* w[12];
};

// ---------------- twiddle tables ----------------
__global__ __launch_bounds__(256) void k_init(float* __restrict__ twt, float* __restrict__ twx) {
  int tid = threadIdx.x;
  for (int i = tid; i < 5 * 64; i += 256) {
    int k = i >> 6, t = i & 63;
    float ang = (float)((k * t) & 63) * (PI2 / 64.f);
    float s, c;
    sincosf(ang, &s, &c);
    twt[2 * i] = c;
    twt[2 * i + 1] = s;
  }
  for (int lev = 0; lev < 6; ++lev) {
    int n = 32 >> lev;
    int kn = n < 10 ? n : 10;
    float* tx = twx + lev * 640;
    for (int i = tid; i < kn * n; i += 256) {
      int j = i / n, m = i % n;
      int k = (kn < 10) ? j : (j < 5 ? j : n - 10 + j);
      float ang = (float)((k * m) % n) * (PI2 / (float)n);
      float s, c;
      sincosf(ang, &s, &c);
      tx[2 * i] = c;
      tx[2 * i + 1] = s;
    }
  }
}

// ---------------- fused wavelet analysis + forward t-DFT (Zt in fp16) ----------------
template <typename T>
__global__ __launch_bounds__(256) void k_wavdft(const T* __restrict__ xin,
                                                const float* __restrict__ ecd,
                                                const float* __restrict__ ecs,
                                                __half* __restrict__ sout,
                                                __half* __restrict__ Zd, __half* __restrict__ Zs,
                                                const float* __restrict__ twt, int n,
                                                float scale) {
  __shared__ float V[72 * 66];     // (p*18 + ds*9 + ch)*66 + t
  __shared__ float Vp[36 * 164];   // [row(p*9+ch)][10][16] padded: stride 164
  __shared__ float tw[640];
  int tid = threadIdx.x;
  for (int i = tid; i < 640; i += 256) tw[i] = twt[i];
  long pos0 = (long)blockIdx.x * 4;
  long total = (long)NB * n * n;
  long nn = (long)n * n;
  int p = tid >> 6, t = tid & 63;
  long pos = pos0 + p;
  if (pos < total) {
    int b = (int)(pos / nn);
    int rem = (int)(pos % nn);
    int xp = rem / n, yp = rem % n;
    int n2 = 2 * n;
    const T* xb = xin + (long)b * 9 * n2 * n2 * 64;
    float dacc[9], sacc[9];
#pragma unroll
    for (int o = 0; o < 9; ++o) { dacc[o] = 0.f; sacc[o] = 0.f; }
#pragma unroll
    for (int q = 0; q < 4; ++q) {
      int X = 2 * xp + (q >> 1), Y = 2 * yp + (q & 1);
      const T* xq = xb + ((long)X * n2 + Y) * 64 + t;
#pragma unroll
      for (int i = 0; i < 9; ++i) {
        float v = (float)xq[(long)i * n2 * n2 * 64];
#pragma unroll
        for (int o = 0; o < 9; ++o) {
          dacc[o] += v * ecd[(q * 9 + i) * 9 + o];
          sacc[o] += v * ecs[(q * 9 + i) * 9 + o];
        }
      }
    }
    long cs = nn * 64;
    __half* sp = sout + (long)b * 9 * cs + (long)rem * 64 + t;
#pragma unroll
    for (int o = 0; o < 9; ++o) {
      sp[o * cs] = __float2half(sacc[o]);
      V[(p * 18 + o) * 66 + t] = dacc[o];
      V[(p * 18 + 9 + o) * 66 + t] = sacc[o];
    }
  }
  __syncthreads();
  int tq = tid & 15;
  float tc[5][4], tsn[5][4];
#pragma unroll
  for (int k = 0; k < 5; ++k)
#pragma unroll
    for (int j = 0; j < 4; ++j) {
      tc[k][j] = tw[2 * (k * 64 + tq * 4 + j)];
      tsn[k][j] = tw[2 * (k * 64 + tq * 4 + j) + 1];
    }
#pragma unroll
  for (int ds = 0; ds < 2; ++ds) {
    for (int slot = tid; slot < 576; slot += 256) {
      int row = slot >> 4;  // p*9 + ch
      const float* vr = &V[((row / 9) * 18 + ds * 9 + (row % 9)) * 66 + tq * 4];
      float v0 = vr[0], v1 = vr[1], v2 = vr[2], v3 = vr[3];
      float* vp = &Vp[row * 164 + tq];
#pragma unroll
      for (int k = 0; k < 5; ++k) {
        float pr = v0 * tc[k][0] + v1 * tc[k][1] + v2 * tc[k][2] + v3 * tc[k][3];
        float pi = -(v0 * tsn[k][0] + v1 * tsn[k][1] + v2 * tsn[k][2] + v3 * tsn[k][3]);
        vp[(2 * k) * 16] = pr;
        vp[(2 * k + 1) * 16] = pi;
      }
    }
    __syncthreads();
    for (int task = tid; task < 360; task += 256) {
      int row = task / 10, j = task % 10;
      const float* vp = &Vp[row * 164 + j * 16];
      float4 a = *reinterpret_cast<const float4*>(vp);
      float4 b4 = *reinterpret_cast<const float4*>(vp + 4);
      float4 c4 = *reinterpret_cast<const float4*>(vp + 8);
      float4 d4 = *reinterpret_cast<const float4*>(vp + 12);
      float s = ((a.x + a.y) + (a.z + a.w)) + ((b4.x + b4.y) + (b4.z + b4.w)) +
                ((c4.x + c4.y) + (c4.z + c4.w)) + ((d4.x + d4.y) + (d4.z + d4.w));
      int pp = row / 9, ch = row % 9;
      long pos2 = pos0 + pp;
      if (pos2 < total) {
        int b = (int)(pos2 / nn);
        int rem = (int)(pos2 % nn);
        __half* o = (ds ? Zs : Zd) + ((long)(b * 9 + ch) * nn + rem) * 10 + j;
        o[0] = __float2half(s * scale);
      }
    }
    __syncthreads();
  }
}

// ---------------- all-level forward y-DFT then x-DFT ----------------
__global__ __launch_bounds__(256) void k_bc_all(const __half* __restrict__ Zt_d,
                                                const __half* __restrict__ Zt_s,
                                                float* __restrict__ Zxy_d,
                                                float* __restrict__ Zxy_s,
                                                const float* __restrict__ twx_all, Levels lv) {
  __shared__ float S1[3840];  // [x*kn+jy][12]
  __shared__ float tx[640];
  int lev = blockIdx.x / 288;
  int r = blockIdx.x % 288;
  int ds = r / 144, bc = r % 144;
  int n = lv.n[lev], kn = lv.kn[lev];
  int tid = threadIdx.x;
  const float* twx = twx_all + lev * 640;
  for (int i = tid; i < kn * n * 2; i += 256) tx[i] = twx[i];
  __syncthreads();
  const __half* in = (ds ? Zt_s : Zt_d) + lv.zt_off[lev] + (long)bc * n * n * 10;
  float* out = (ds ? Zxy_s : Zxy_d) + lv.zxy_off[lev] + (long)bc * kn * kn * 10;
  int t1n = n * kn;
  for (int task = tid; task < t1n; task += 256) {
    int jy = task % kn, x = task / kn;
    float acc[10];
#pragma unroll
    for (int j = 0; j < 10; ++j) acc[j] = 0.f;
    const __half2* row2 = reinterpret_cast<const __half2*>(in + (long)x * n * 10);
    for (int y = 0; y < n; ++y) {
      float2 cs2 = *reinterpret_cast<const float2*>(&tx[2 * (jy * n + y)]);
#pragma unroll
      for (int kz = 0; kz < 5; ++kz) {
        float2 z = __half22float2(row2[y * 5 + kz]);
        acc[2 * kz] += z.x * cs2.x + z.y * cs2.y;
        acc[2 * kz + 1] += z.y * cs2.x - z.x * cs2.y;
      }
    }
    float* s1 = &S1[(x * kn + jy) * 12];
#pragma unroll
    for (int j = 0; j < 10; ++j) s1[j] = acc[j];
  }
  __syncthreads();
  int t2n = kn * kn;
  for (int task = tid; task < t2n; task += 256) {
    int jy = task % kn, jx = task / kn;
    float acc[10];
#pragma unroll
    for (int j = 0; j < 10; ++j) acc[j] = 0.f;
    for (int x = 0; x < n; ++x) {
      const float* zr = &S1[(x * kn + jy) * 12];
      float2 cs2 = *reinterpret_cast<const float2*>(&tx[2 * (jx * n + x)]);
#pragma unroll
      for (int kz = 0; kz < 5; ++kz) {
        float zx = zr[2 * kz], zy = zr[2 * kz + 1];
        acc[2 * kz] += zx * cs2.x + zy * cs2.y;
        acc[2 * kz + 1] += zy * cs2.x - zx * cs2.y;
      }
    }
    float* o = out + (jx * kn + jy) * 10;
#pragma unroll
    for (int j = 0; j < 10; ++j) o[j] = acc[j];
  }
}

// ---------------- all-level fused mode-mix + inverse expand x,y ----------------
__global__ __launch_bounds__(256) void k_efmix_all(const float* __restrict__ Zxy_d,
                                                   const float* __restrict__ Zxy_s,
                                                   __half* __restrict__ Z6a,
                                                   __half* __restrict__ Z6b,
                                                   __half* __restrict__ Z6c, WArgs wa,
                                                   const float* __restrict__ twx_all,
                                                   Levels lv) {
  __shared__ float zm[1200];   // [jx*kn+jy][12]
  __shared__ float S1[3840];   // [x*kn+jy][12]
  __shared__ float tx[640];
  int lev = blockIdx.x / 432;
  int r = blockIdx.x % 432;
  int batch = r / 144;
  int rr = r % 144;
  int b = rr / 9, o = rr % 9;
  int n = lv.n[lev], kn = lv.kn[lev];
  int nm = kn * kn * 5;
  int tid = threadIdx.x;
  const float* twx = twx_all + lev * 640;
  const float* in = (batch == 1 ? Zxy_s : Zxy_d) + lv.zxy_off[lev] + (long)b * 9 * nm * 2;
  const float2* in2 = reinterpret_cast<const float2*>(in);
  __half* out = (batch == 0 ? Z6a : batch == 1 ? Z6b : Z6c) + lv.z6_off[lev] +
                ((long)(b * 9 + o)) * n * n * 10;
  for (int i = tid; i < kn * n * 2; i += 256) tx[i] = twx[i];
  __syncthreads();
  int l1 = (5 < n / 2 + 1) ? 5 : n / 2 + 1;
  for (int m = tid; m < nm; m += 256) {
    int kz = m % 5, jy = (m / 5) % kn, jx = m / (5 * kn);
    int kx = (kn < 10) ? jx : (jx < 5 ? jx : n - 10 + jx);
    int ky = (kn < 10) ? jy : (jy < 5 ? jy : n - 10 + jy);
    bool lx = kx < l1, hx = kx >= n - l1, ly = ky < l1, hy = ky >= n - l1;
    const float* wsel;
    int wx, wy;
    if (hx && hy) { wsel = wa.w[batch * 4 + 3]; wx = kx - (n - l1); wy = ky - (n - l1); }
    else if (lx && hy) { wsel = wa.w[batch * 4 + 2]; wx = kx; wy = ky - (n - l1); }
    else if (hx && ly) { wsel = wa.w[batch * 4 + 1]; wx = kx - (n - l1); wy = ky; }
    else { wsel = wa.w[batch * 4 + 0]; wx = kx; wy = ky; }
    const float* wp = wsel + o * 250 + wx * 50 + wy * 10 + kz * 2;
    float sr = 0.f, si = 0.f;
#pragma unroll
    for (int i = 0; i < 9; ++i) {
      float2 z = in2[i * nm + m];
      float2 w2 = *reinterpret_cast<const float2*>(&wp[i * 2250]);
      sr += z.x * w2.x - z.y * w2.y;
      si += z.x * w2.y + z.y * w2.x;
    }
    zm[(jx * kn + jy) * 12 + 2 * kz] = sr;
    zm[(jx * kn + jy) * 12 + 2 * kz + 1] = si;
  }
  __syncthreads();
  int t1n = n * kn;
  for (int task = tid; task < t1n; task += 256) {
    int jy = task % kn, x = task / kn;
    float acc[10];
#pragma unroll
    for (int j = 0; j < 10; ++j) acc[j] = 0.f;
    for (int jx = 0; jx < kn; ++jx) {
      const float* zr = &zm[(jx * kn + jy) * 12];
      float2 cs2 = *reinterpret_cast<const float2*>(&tx[2 * (jx * n + x)]);
#pragma unroll
      for (int kz = 0; kz < 5; ++kz) {
        float zx = zr[2 * kz], zy = zr[2 * kz + 1];
        acc[2 * kz] += zx * cs2.x - zy * cs2.y;
        acc[2 * kz + 1] += zx * cs2.y + zy * cs2.x;
      }
    }
    float* s1 = &S1[(x * kn + jy) * 12];
#pragma unroll
    for (int j = 0; j < 10; ++j) s1[j] = acc[j];
  }
  __syncthreads();
  int t2n = n * n;
  for (int task = tid; task < t2n; task += 256) {
    int y = task % n, x = task / n;
    float acc[10];
#pragma unroll
    for (int j = 0; j < 10; ++j) acc[j] = 0.f;
    for (int jy = 0; jy < kn; ++jy) {
      const float* zr = &S1[(x * kn + jy) * 12];
      float2 cs2 = *reinterpret_cast<const float2*>(&tx[2 * (jy * n + y)]);
#pragma unroll
      for (int kz = 0; kz < 5; ++kz) {
        float zx = zr[2 * kz], zy = zr[2 * kz + 1];
        acc[2 * kz] += zx * cs2.x - zy * cs2.y;
        acc[2 * kz + 1] += zx * cs2.y + zy * cs2.x;
      }
    }
    __half* op = out + (long)(x * n + y) * 10;
#pragma unroll
    for (int kz = 0; kz < 5; ++kz)
      *reinterpret_cast<__half2*>(op + 2 * kz) = __floats2half2_rn(acc[2 * kz], acc[2 * kz + 1]);
  }
}

// ---------------- levels 2-5 inverse-t(c2r) + ReLU + lo conv ----------------
__global__ __launch_bounds__(256) void k_gh3_all(const __half* __restrict__ Z6a,
                                                 const __half* __restrict__ Z6b,
                                                 const __half* __restrict__ Z6c,
                                                 const float* __restrict__ a_low,
                                                 const float* __restrict__ a_lob,
                                                 const float* __restrict__ b_low,
                                                 const float* __restrict__ b_lob,
                                                 const float* __restrict__ c_low,
                                                 const float* __restrict__ c_lob,
                                                 __half* __restrict__ Ud,
                                                 __half* __restrict__ Us,
                                                 const float* __restrict__ twt, Levels lv) {
  __shared__ float tw[640];
  __shared__ float zz[3][4][90];
  int tid = threadIdx.x;
  for (int i = tid; i < 640; i += 256) tw[i] = twt[i];
  int lev = 2;
  while (lev < 5 && (int)blockIdx.x >= lv.gstart[lev + 1]) ++lev;
  int n = lv.n[lev];
  float scale = lv.scale[lev];
  long pos0 = (long)(blockIdx.x - lv.gstart[lev]) * 4;
  long total = (long)NB * n * n;
  const __half* zbuf[3] = {Z6a + lv.z6_off[lev], Z6b + lv.z6_off[lev], Z6c + lv.z6_off[lev]};
  for (int i = tid; i < 540; i += 256) {
    int bi = i / 180;
    int rr2 = i % 180;
    int p = rr2 / 45;
    int q = rr2 % 45;
    int ch = q / 5, kz = q % 5;
    long pos = pos0 + p;
    if (pos < total) {
      int b = (int)(pos / (n * n));
      int rem = (int)(pos % (n * n));
      const __half2* src = reinterpret_cast<const __half2*>(
          zbuf[bi] + ((long)(b * 9 + ch) * n * n + rem) * 10 + 2 * kz);
      float2 f = __half22float2(*src);
      *reinterpret_cast<float2*>(&zz[bi][p][ch * 10 + 2 * kz]) = f;
    }
  }
  __syncthreads();
  int p = tid / 64, t = tid & 63;
  long pos = pos0 + p;
  if (pos >= total) return;
  int b = (int)(pos / (n * n));
  int rem = (int)(pos % (n * n));
  float tc[4], tsn[4];
#pragma unroll
  for (int k = 1; k < 5; ++k) {
    float2 cs2 = *reinterpret_cast<const float2*>(&tw[2 * (k * 64 + t)]);
    tc[k - 1] = cs2.x;
    tsn[k - 1] = cs2.y;
  }
  float rva[9], rvb[9], rvc[9];
#pragma unroll
  for (int i = 0; i < 9; ++i) {
    const float* za = &zz[0][p][i * 10];
    const float* zb = &zz[1][p][i * 10];
    const float* zc = &zz[2][p][i * 10];
    float va = za[0], vb = zb[0], vc = zc[0];
#pragma unroll
    for (int k = 1; k < 5; ++k) {
      float2 za2 = *reinterpret_cast<const float2*>(&za[2 * k]);
      float2 zb2 = *reinterpret_cast<const float2*>(&zb[2 * k]);
      float2 zc2 = *reinterpret_cast<const float2*>(&zc[2 * k]);
      va += 2.f * (za2.x * tc[k - 1] - za2.y * tsn[k - 1]);
      vb += 2.f * (zb2.x * tc[k - 1] - zb2.y * tsn[k - 1]);
      vc += 2.f * (zc2.x * tc[k - 1] - zc2.y * tsn[k - 1]);
    }
    rva[i] = fmaxf(va * scale, 0.f);
    rvb[i] = fmaxf(vb * scale, 0.f);
    rvc[i] = fmaxf(vc * scale, 0.f);
  }
  long cs = (long)n * n * 64;
  long ob = (long)b * 9 * cs + (long)rem * 64 + t;
  __half* ud = Ud + lv.u_off[lev];
  __half* us = Us + lv.u_off[lev];
#pragma unroll
  for (int o = 0; o < 9; ++o) {
    float du = a_lob[o] + b_lob[o];
    float usv = c_lob[o];
#pragma unroll
    for (int i = 0; i < 9; ++i) {
      du += a_low[o * 9 + i] * rva[i] + b_low[o * 9 + i] * rvb[i];
      usv += c_low[o * 9 + i] * rvc[i];
    }
    ud[ob + o * cs] = __float2half(du);
    us[ob + o * cs] = __float2half(usv);
  }
}

// ---------------- single-pos recon step helper (o split across 4 warps) ----------------
__device__ inline void step1pos_par(const float* __restrict__ in, float* __restrict__ outp,
                                    const __half* __restrict__ us, const __half* __restrict__ ud,
                                    long chs, const float* __restrict__ rc, int t, int p) {
  float cat[18];
#pragma unroll
  for (int i = 0; i < 9; ++i) cat[i] = in[i * 64 + t] + __half2float(us[chs * i + t]);
#pragma unroll
  for (int i = 0; i < 9; ++i) cat[9 + i] = __half2float(ud[chs * i + t]);
  for (int o = p; o < 9; o += 4) {
    float s = 0.f;
#pragma unroll
    for (int i = 0; i < 18; ++i) s += cat[i] * rc[i * 9 + o];
    outp[o * 64 + t] = s;
  }
}

// ---------------- recon part A: t0 + levels 5..2 -> G2 [b][9][16x16][64] fp32 ----------
__global__ __launch_bounds__(256) void k_recon_a(
    const __half* __restrict__ s5, const float* __restrict__ t0w,
    const float* __restrict__ t0b, const __half* __restrict__ Ud,
    const __half* __restrict__ Us, const float* __restrict__ rcee,
    const float* __restrict__ rceo, const float* __restrict__ roe_,
    const float* __restrict__ roo_, float* __restrict__ G2, Levels lv) {
  __shared__ float A[576];
  __shared__ float Bq[576];
  int tid = threadIdx.x;
  int b = blockIdx.x >> 6;
  int T = blockIdx.x & 63;
  int tx = T >> 3, ty = T & 7;
  const float* rcw[4] = {rcee, rceo, roe_, roo_};
  int pg = tid >> 6, t64 = tid & 63;

  {  // t0
    float v[9];
#pragma unroll
    for (int i = 0; i < 9; ++i) v[i] = __half2float(s5[((long)b * 9 + i) * 64 + t64]);
    for (int o = pg; o < 9; o += 4) {
      float s = t0b[o];
#pragma unroll
      for (int i = 0; i < 9; ++i) s += t0w[o * 9 + i] * v[i];
      A[o * 64 + t64] = s;
    }
  }
  __syncthreads();
  {  // step 5
    int sel = ((tx >> 2) & 1) * 2 + ((ty >> 2) & 1);
    long base = lv.u_off[5] + (long)b * 9 * 64;
    step1pos_par(A, Bq, Us + base, Ud + base, 64, rcw[sel], t64, pg);
  }
  __syncthreads();
  {  // step 4
    int ip = (tx >> 2) * 2 + (ty >> 2);
    int sel = ((tx >> 1) & 1) * 2 + ((ty >> 1) & 1);
    long base = lv.u_off[4] + ((long)b * 9 * 4 + ip) * 64;
    step1pos_par(Bq, A, Us + base, Ud + base, 4 * 64, rcw[sel], t64, pg);
  }
  __syncthreads();
  {  // step 3
    int ip = (tx >> 1) * 4 + (ty >> 1);
    int sel = (tx & 1) * 2 + (ty & 1);
    long base = lv.u_off[3] + ((long)b * 9 * 16 + ip) * 64;
    step1pos_par(A, Bq, Us + base, Ud + base, 16 * 64, rcw[sel], t64, pg);
  }
  __syncthreads();
  {  // step 2: 4 quadrants -> global G2
    int ip = tx * 8 + ty;
    long base = lv.u_off[2] + ((long)b * 9 * 64 + ip) * 64;
    float cat[18];
#pragma unroll
    for (int i = 0; i < 9; ++i)
      cat[i] = Bq[i * 64 + t64] + __half2float(Us[base + (long)64 * 64 * i + t64]);
#pragma unroll
    for (int i = 0; i < 9; ++i) cat[9 + i] = __half2float(Ud[base + (long)64 * 64 * i + t64]);
    const float* rc = rcw[pg];
    int p2 = (2 * tx + (pg >> 1)) * 16 + (2 * ty + (pg & 1));
#pragma unroll
    for (int o = 0; o < 9; ++o) {
      float s = 0.f;
#pragma unroll
      for (int i = 0; i < 18; ++i) s += cat[i] * rc[i * 9 + o];
      G2[((long)(b * 9 + o) * 256 + p2) * 64 + t64] = s;
    }
  }
}

// ---------------- recon part B: levels 1+0 with fused gh3-lev1 AND gh3-lev0 -----------
// block = (b, lev1-input pos p1 on 16x16). threads = 4 children (a,c) x 64 t.
__global__ __launch_bounds__(256) void k_recon_b(
    const float* __restrict__ G2, const __half* __restrict__ Z6a,
    const __half* __restrict__ Z6b, const __half* __restrict__ Z6c,
    const float* __restrict__ a_low, const float* __restrict__ a_lob,
    const float* __restrict__ b_low, const float* __restrict__ b_lob,
    const float* __restrict__ c_low, const float* __restrict__ c_lob,
    const float* __restrict__ twt, float scale0, float scale1,
    const float* __restrict__ rcee, const float* __restrict__ rceo,
    const float* __restrict__ roe_, const float* __restrict__ roo_,
    float* __restrict__ out, Levels lv) {
  __shared__ float tw[640];
  __shared__ float zz[3][4][90];  // Z6 lev0, per child
  __shared__ float z1[3][90];     // Z6 lev1, pos p1
  int tid = threadIdx.x;
  int bid = blockIdx.x;
  int b = bid >> 8;
  int p1 = bid & 255;
  int g1x = p1 >> 4, g1y = p1 & 15;
  int grp = tid >> 6, t = tid & 63;
  int a = grp >> 1, c = grp & 1;
  const float* rcw[4] = {rcee, rceo, roe_, roo_};

  for (int i = tid; i < 640; i += 256) tw[i] = twt[i];
  {
    const __half* zb3[3] = {Z6a, Z6b, Z6c};
    // lev0 staging: 540 half2 loads
    for (int i = tid; i < 540; i += 256) {
      int bi = i / 180;
      int rr2 = i % 180;
      int g = rr2 / 45;
      int q = rr2 % 45;
      int ch = q / 5, kz = q % 5;
      int x0 = 2 * g1x + (g >> 1), y0 = 2 * g1y + (g & 1);
      int rem = x0 * 32 + y0;
      const __half2* src = reinterpret_cast<const __half2*>(
          zb3[bi] + ((long)(b * 9 + ch) * 1024 + rem) * 10 + 2 * kz);
      float2 f = __half22float2(*src);
      *reinterpret_cast<float2*>(&zz[bi][g][ch * 10 + 2 * kz]) = f;
    }
    // lev1 staging: 135 half2 loads (z6_off[1])
    for (int i = tid; i < 135; i += 256) {
      int bi = i / 45;
      int q = i % 45;
      int ch = q / 5, kz = q % 5;
      const __half2* src = reinterpret_cast<const __half2*>(
          zb3[bi] + lv.z6_off[1] + ((long)(b * 9 + ch) * 256 + p1) * 10 + 2 * kz);
      float2 f = __half22float2(*src);
      *reinterpret_cast<float2*>(&z1[bi][ch * 10 + 2 * kz]) = f;
    }
  }
  __syncthreads();

  float tc[4], tsn[4];
#pragma unroll
  for (int k = 1; k < 5; ++k) {
    float2 cs2 = *reinterpret_cast<const float2*>(&tw[2 * (k * 64 + t)]);
    tc[k - 1] = cs2.x;
    tsn[k - 1] = cs2.y;
  }

  // gh3-lev1 in-register: Us1/Ud1 at (p1, t)
  float us1[9], ud1[9];
  {
    float rva[9], rvb[9], rvc[9];
#pragma unroll
    for (int i = 0; i < 9; ++i) {
      const float* za = &z1[0][i * 10];
      const float* zb = &z1[1][i * 10];
      const float* zc = &z1[2][i * 10];
      float va = za[0], vb = zb[0], vc = zc[0];
#pragma unroll
      for (int k = 1; k < 5; ++k) {
        float2 za2 = *reinterpret_cast<const float2*>(&za[2 * k]);
        float2 zb2 = *reinterpret_cast<const float2*>(&zb[2 * k]);
        float2 zc2 = *reinterpret_cast<const float2*>(&zc[2 * k]);
        va += 2.f * (za2.x * tc[k - 1] - za2.y * tsn[k - 1]);
        vb += 2.f * (zb2.x * tc[k - 1] - zb2.y * tsn[k - 1]);
        vc += 2.f * (zc2.x * tc[k - 1] - zc2.y * tsn[k - 1]);
      }
      rva[i] = fmaxf(va * scale1, 0.f);
      rvb[i] = fmaxf(vb * scale1, 0.f);
      rvc[i] = fmaxf(vc * scale1, 0.f);
    }
#pragma unroll
    for (int o = 0; o < 9; ++o) {
      float du = a_lob[o] + b_lob[o];
      float usv = c_lob[o];
#pragma unroll
      for (int i = 0; i < 9; ++i) {
        du += a_low[o * 9 + i] * rva[i] + b_low[o * 9 + i] * rvb[i];
        usv += c_low[o * 9 + i] * rvc[i];
      }
      us1[o] = usv;
      ud1[o] = du;
    }
  }

  // step 1: lev1 recon at input pos p1, child (a,c)
  float out9[9];
  {
    const float* rc = rcw[a * 2 + c];
    float cat[18];
#pragma unroll
    for (int i = 0; i < 9; ++i)
      cat[i] = G2[((long)(b * 9 + i) * 256 + p1) * 64 + t] + us1[i];
#pragma unroll
    for (int i = 0; i < 9; ++i) cat[9 + i] = ud1[i];
#pragma unroll
    for (int o = 0; o < 9; ++o) {
      float s = 0.f;
#pragma unroll
      for (int i = 0; i < 18; ++i) s += cat[i] * rc[i * 9 + o];
      out9[o] = s;
    }
  }
  // step 0 with fused gh3-lev0
  {
    float rva[9], rvb[9], rvc[9];
#pragma unroll
    for (int i = 0; i < 9; ++i) {
      const float* za = &zz[0][grp][i * 10];
      const float* zb = &zz[1][grp][i * 10];
      const float* zc = &zz[2][grp][i * 10];
      float va = za[0], vb = zb[0], vc = zc[0];
#pragma unroll
      for (int k = 1; k < 5; ++k) {
        float2 za2 = *reinterpret_cast<const float2*>(&za[2 * k]);
        float2 zb2 = *reinterpret_cast<const float2*>(&zb[2 * k]);
        float2 zc2 = *reinterpret_cast<const float2*>(&zc[2 * k]);
        va += 2.f * (za2.x * tc[k - 1] - za2.y * tsn[k - 1]);
        vb += 2.f * (zb2.x * tc[k - 1] - zb2.y * tsn[k - 1]);
        vc += 2.f * (zc2.x * tc[k - 1] - zc2.y * tsn[k - 1]);
      }
      rva[i] = fmaxf(va * scale0, 0.f);
      rvb[i] = fmaxf(vb * scale0, 0.f);
      rvc[i] = fmaxf(vc * scale0, 0.f);
    }
    float cat[18];
#pragma unroll
    for (int o = 0; o < 9; ++o) {
      float du = a_lob[o] + b_lob[o];
      float usv = c_lob[o];
#pragma unroll
      for (int i = 0; i < 9; ++i) {
        du += a_low[o * 9 + i] * rva[i] + b_low[o * 9 + i] * rvb[i];
        usv += c_low[o * 9 + i] * rvc[i];
      }
      cat[o] = out9[o] + usv;
      cat[9 + o] = du;
    }
    int x0 = 2 * g1x + a, y0 = 2 * g1y + c;
#pragma unroll
    for (int rx = 0; rx < 2; ++rx)
#pragma unroll
      for (int ry = 0; ry < 2; ++ry) {
        const float* rc = rcw[rx * 2 + ry];
        int X = 2 * x0 + rx, Y = 2 * y0 + ry;
#pragma unroll
        for (int o = 0; o < 9; ++o) {
          float s = 0.f;
#pragma unroll
          for (int i = 0; i < 18; ++i) s += cat[i] * rc[i * 9 + o];
          out[((((long)b * 9 + o) * 64 + X) * 64 + Y) * 64 + t] = s;
        }
      }
  }
}

extern "C" void kernel_launch(void* const* d_in, const int* in_sizes, int n_in, void* d_out,
                              int out_size, void* d_ws, size_t ws_size, hipStream_t stream) {
  (void)in_sizes; (void)n_in; (void)out_size; (void)ws_size;
  const float* x = (const float*)d_in[0];
  const float* aw[4] = {(const float*)d_in[1], (const float*)d_in[2], (const float*)d_in[3],
                        (const float*)d_in[4]};
  const float* a_low = (const float*)d_in[5];
  const float* a_lob = (const float*)d_in[6];
  const float* bw[4] = {(const float*)d_in[7], (const float*)d_in[8], (const float*)d_in[9],
                        (const float*)d_in[10]};
  const float* b_low = (const float*)d_in[11];
  const float* b_lob = (const float*)d_in[12];
  const float* cw[4] = {(const float*)d_in[13], (const float*)d_in[14], (const float*)d_in[15],
                        (const float*)d_in[16]};
  const float* c_low = (const float*)d_in[17];
  const float* c_lob = (const float*)d_in[18];
  const float* t0w = (const float*)d_in[19];
  const float* t0b = (const float*)d_in[20];
  const float* ecs = (const float*)d_in[21];
  const float* ecd = (const float*)d_in[22];
  const float* rcee = (const float*)d_in[23];
  const float* rceo = (const float*)d_in[24];
  const float* rcoe = (const float*)d_in[25];
  const float* rcoo = (const float*)d_in[26];

  Levels lv;
  {
    int zt = 0, zxy = 0;
    static const int uoff[6] = {0, 9437184, 11796480, 12386304, 12533760, 12570624};
    for (int lev = 0; lev < 6; ++lev) {
      int n = 32 >> lev;
      int kn = n < 10 ? n : 10;
      lv.n[lev] = n;
      lv.kn[lev] = kn;
      lv.zt_off[lev] = zt;
      lv.zxy_off[lev] = zxy;
      lv.z6_off[lev] = zt;
      lv.u_off[lev] = uoff[lev];
      lv.scale[lev] = 1.f / sqrtf((float)(n * n * 64));
      zt += NB * 9 * n * n * 10;
      zxy += NB * 9 * kn * kn * 10;
    }
    // gh3 grid over levels 2..5 only
    int gh = 0;
    lv.gstart[0] = 0;
    lv.gstart[1] = 0;
    for (int lev = 2; lev < 6; ++lev) {
      lv.gstart[lev] = gh;
      gh += (NB * (32 >> lev) * (32 >> lev) + 3) / 4;
    }
    lv.gstart[6] = gh;
  }

  char* base = (char*)d_ws;
  size_t ob = 0;
  auto allocF = [&](size_t ne) { float* p = (float*)(base + ob); ob += ne * 4; return p; };
  auto allocH = [&](size_t ne) {
    __half* p = (__half*)(base + ob);
    ob += ((ne + 1) & ~(size_t)1) * 2;
    return p;
  };
  float* twt = allocF(640);
  float* twx = allocF(3840);
  float* Zxy_d = allocF(410400);
  float* Zxy_s = allocF(410400);
  float* G2 = allocF(2359296);
  __half* Zt_d = allocH(1965600);
  __half* Zt_s = allocH(1965600);
  __half* s_a = allocH(9437184);
  __half* s_b = allocH(9437184);
  __half* Z6a = allocH(1965600);
  __half* Z6b = allocH(1965600);
  __half* Z6c = allocH(1965600);
  __half* Ud = allocH(12579840);
  __half* Us = allocH(12579840);

  k_init<<<1, 256, 0, stream>>>(twt, twx);

  for (int lev = 0; lev < 6; ++lev) {
    int n = 32 >> lev;
    int nblk = (NB * n * n + 3) / 4;
    __half* s_cur = (lev & 1) ? s_b : s_a;
    __half* ztd = Zt_d + lv.zt_off[lev];
    __half* zts = Zt_s + lv.zt_off[lev];
    if (lev == 0)
      k_wavdft<float><<<nblk, 256, 0, stream>>>(x, ecd, ecs, s_cur, ztd, zts, twt, n,
                                                lv.scale[lev]);
    else
      k_wavdft<__half><<<nblk, 256, 0, stream>>>((lev & 1) ? s_a : s_b, ecd, ecs, s_cur, ztd,
                                                 zts, twt, n, lv.scale[lev]);
  }

  k_bc_all<<<6 * 288, 256, 0, stream>>>(Zt_d, Zt_s, Zxy_d, Zxy_s, twx, lv);
  WArgs wa;
  for (int j = 0; j < 4; ++j) { wa.w[j] = aw[j]; wa.w[4 + j] = bw[j]; wa.w[8 + j] = cw[j]; }
  k_efmix_all<<<6 * 432, 256, 0, stream>>>(Zxy_d, Zxy_s, Z6a, Z6b, Z6c, wa, twx, lv);
  k_gh3_all<<<lv.gstart[6], 256, 0, stream>>>(Z6a, Z6b, Z6c, a_low, a_lob, b_low, b_lob, c_low,
                                              c_lob, Ud, Us, twt, lv);

  k_recon_a<<<NB * 64, 256, 0, stream>>>(s_b, t0w, t0b, Ud, Us, rcee, rceo, rcoe, rcoo, G2,
                                         lv);
  k_recon_b<<<NB * 256, 256, 0, stream>>>(G2, Z6a, Z6b, Z6c, a_low, a_lob, b_low, b_lob,
                                          c_low, c_lob, twt, lv.scale[0], lv.scale[1], rcee,
                                          rceo, rcoe, rcoo, (float*)d_out, lv);
}

// Round 16
// 253.737 us; speedup vs baseline: 1.4686x; 1.4686x over previous
//
#include <hip/hip_runtime.h>
#include <hip/hip_fp16.h>
#include <math.h>

#define NB 16
#define PI2 6.28318530717958647692f

struct Levels {
  int n[6], kn[6];
  int zt_off[6];   // float elements
  int zxy_off[6];  // float elements
  int z6_off[6];   // half elements
  int u_off[6];    // half elements
  int gstart[7];
  float scale[6];
};
struct WArgs {
  const float* w[12];
};

// ---------------- twiddle tables ----------------
__global__ __launch_bounds__(256) void k_init(float* __restrict__ twt, float* __restrict__ twx) {
  int tid = threadIdx.x;
  for (int i = tid; i < 5 * 64; i += 256) {
    int k = i >> 6, t = i & 63;
    float ang = (float)((k * t) & 63) * (PI2 / 64.f);
    float s, c;
    sincosf(ang, &s, &c);
    twt[2 * i] = c;
    twt[2 * i + 1] = s;
  }
  for (int lev = 0; lev < 6; ++lev) {
    int n = 32 >> lev;
    int kn = n < 10 ? n : 10;
    float* tx = twx + lev * 640;
    for (int i = tid; i < kn * n; i += 256) {
      int j = i / n, m = i % n;
      int k = (kn < 10) ? j : (j < 5 ? j : n - 10 + j);
      float ang = (float)((k * m) % n) * (PI2 / (float)n);
      float s, c;
      sincosf(ang, &s, &c);
      tx[2 * i] = c;
      tx[2 * i + 1] = s;
    }
  }
}

// ---------------- fused wavelet analysis + forward t-DFT ----------------
template <typename T>
__global__ __launch_bounds__(256) void k_wavdft(const T* __restrict__ xin,
                                                const float* __restrict__ ecd,
                                                const float* __restrict__ ecs,
                                                __half* __restrict__ sout,
                                                float* __restrict__ Zd, float* __restrict__ Zs,
                                                const float* __restrict__ twt, int n,
                                                float scale) {
  __shared__ float V[72 * 66];     // (p*18 + ds*9 + ch)*66 + t
  __shared__ float Vp[36 * 164];   // [row(p*9+ch)][10][16] padded: stride 164
  __shared__ float tw[640];
  int tid = threadIdx.x;
  for (int i = tid; i < 640; i += 256) tw[i] = twt[i];
  long pos0 = (long)blockIdx.x * 4;
  long total = (long)NB * n * n;
  long nn = (long)n * n;
  int p = tid >> 6, t = tid & 63;
  long pos = pos0 + p;
  if (pos < total) {
    int b = (int)(pos / nn);
    int rem = (int)(pos % nn);
    int xp = rem / n, yp = rem % n;
    int n2 = 2 * n;
    const T* xb = xin + (long)b * 9 * n2 * n2 * 64;
    float dacc[9], sacc[9];
#pragma unroll
    for (int o = 0; o < 9; ++o) { dacc[o] = 0.f; sacc[o] = 0.f; }
#pragma unroll
    for (int q = 0; q < 4; ++q) {
      int X = 2 * xp + (q >> 1), Y = 2 * yp + (q & 1);
      const T* xq = xb + ((long)X * n2 + Y) * 64 + t;
#pragma unroll
      for (int i = 0; i < 9; ++i) {
        float v = (float)xq[(long)i * n2 * n2 * 64];
#pragma unroll
        for (int o = 0; o < 9; ++o) {
          dacc[o] += v * ecd[(q * 9 + i) * 9 + o];
          sacc[o] += v * ecs[(q * 9 + i) * 9 + o];
        }
      }
    }
    long cs = nn * 64;
    __half* sp = sout + (long)b * 9 * cs + (long)rem * 64 + t;
#pragma unroll
    for (int o = 0; o < 9; ++o) {
      sp[o * cs] = __float2half(sacc[o]);
      V[(p * 18 + o) * 66 + t] = dacc[o];
      V[(p * 18 + 9 + o) * 66 + t] = sacc[o];
    }
  }
  __syncthreads();
  int tq = tid & 15;
  float tc[5][4], tsn[5][4];
#pragma unroll
  for (int k = 0; k < 5; ++k)
#pragma unroll
    for (int j = 0; j < 4; ++j) {
      tc[k][j] = tw[2 * (k * 64 + tq * 4 + j)];
      tsn[k][j] = tw[2 * (k * 64 + tq * 4 + j) + 1];
    }
#pragma unroll
  for (int ds = 0; ds < 2; ++ds) {
    for (int slot = tid; slot < 576; slot += 256) {
      int row = slot >> 4;  // p*9 + ch
      const float* vr = &V[((row / 9) * 18 + ds * 9 + (row % 9)) * 66 + tq * 4];
      float v0 = vr[0], v1 = vr[1], v2 = vr[2], v3 = vr[3];
      float* vp = &Vp[row * 164 + tq];
#pragma unroll
      for (int k = 0; k < 5; ++k) {
        float pr = v0 * tc[k][0] + v1 * tc[k][1] + v2 * tc[k][2] + v3 * tc[k][3];
        float pi = -(v0 * tsn[k][0] + v1 * tsn[k][1] + v2 * tsn[k][2] + v3 * tsn[k][3]);
        vp[(2 * k) * 16] = pr;
        vp[(2 * k + 1) * 16] = pi;
      }
    }
    __syncthreads();
    for (int task = tid; task < 360; task += 256) {
      int row = task / 10, j = task % 10;
      const float* vp = &Vp[row * 164 + j * 16];
      float4 a = *reinterpret_cast<const float4*>(vp);
      float4 b4 = *reinterpret_cast<const float4*>(vp + 4);
      float4 c4 = *reinterpret_cast<const float4*>(vp + 8);
      float4 d4 = *reinterpret_cast<const float4*>(vp + 12);
      float s = ((a.x + a.y) + (a.z + a.w)) + ((b4.x + b4.y) + (b4.z + b4.w)) +
                ((c4.x + c4.y) + (c4.z + c4.w)) + ((d4.x + d4.y) + (d4.z + d4.w));
      int pp = row / 9, ch = row % 9;
      long pos2 = pos0 + pp;
      if (pos2 < total) {
        int b = (int)(pos2 / nn);
        int rem = (int)(pos2 % nn);
        float* o = (ds ? Zs : Zd) + ((long)(b * 9 + ch) * nn + rem) * 10 + j;
        o[0] = s * scale;
      }
    }
    __syncthreads();
  }
}

// ---------------- all-level forward y-DFT then x-DFT (padded kz-12 layout) -------------
__global__ __launch_bounds__(256) void k_bc_all(const float* __restrict__ Zt_d,
                                                const float* __restrict__ Zt_s,
                                                float* __restrict__ Zxy_d,
                                                float* __restrict__ Zxy_s,
                                                const float* __restrict__ twx_all, Levels lv) {
  __shared__ float S1[3840];  // [x*kn+jy][12]
  __shared__ float tx[640];
  int lev = blockIdx.x / 288;
  int r = blockIdx.x % 288;
  int ds = r / 144, bc = r % 144;
  int n = lv.n[lev], kn = lv.kn[lev];
  int tid = threadIdx.x;
  const float* twx = twx_all + lev * 640;
  for (int i = tid; i < kn * n * 2; i += 256) tx[i] = twx[i];
  __syncthreads();
  const float* in = (ds ? Zt_s : Zt_d) + lv.zt_off[lev] + (long)bc * n * n * 10;
  float* out = (ds ? Zxy_s : Zxy_d) + lv.zxy_off[lev] + (long)bc * kn * kn * 10;
  int t1n = n * kn;
  for (int task = tid; task < t1n; task += 256) {
    int jy = task % kn, x = task / kn;
    float acc[10];
#pragma unroll
    for (int j = 0; j < 10; ++j) acc[j] = 0.f;
    const float2* row2 = reinterpret_cast<const float2*>(in + (long)x * n * 10);
    for (int y = 0; y < n; ++y) {
      float2 cs2 = *reinterpret_cast<const float2*>(&tx[2 * (jy * n + y)]);
#pragma unroll
      for (int kz = 0; kz < 5; ++kz) {
        float2 z = row2[y * 5 + kz];
        acc[2 * kz] += z.x * cs2.x + z.y * cs2.y;
        acc[2 * kz + 1] += z.y * cs2.x - z.x * cs2.y;
      }
    }
    float* s1 = &S1[(x * kn + jy) * 12];
#pragma unroll
    for (int j = 0; j < 10; ++j) s1[j] = acc[j];
  }
  __syncthreads();
  int t2n = kn * kn;
  for (int task = tid; task < t2n; task += 256) {
    int jy = task % kn, jx = task / kn;
    float acc[10];
#pragma unroll
    for (int j = 0; j < 10; ++j) acc[j] = 0.f;
    for (int x = 0; x < n; ++x) {
      const float* zr = &S1[(x * kn + jy) * 12];
      float2 cs2 = *reinterpret_cast<const float2*>(&tx[2 * (jx * n + x)]);
#pragma unroll
      for (int kz = 0; kz < 5; ++kz) {
        float zx = zr[2 * kz], zy = zr[2 * kz + 1];
        acc[2 * kz] += zx * cs2.x + zy * cs2.y;
        acc[2 * kz + 1] += zy * cs2.x - zx * cs2.y;
      }
    }
    float* o = out + (jx * kn + jy) * 10;
#pragma unroll
    for (int j = 0; j < 10; ++j) o[j] = acc[j];
  }
}

// ---------------- all-level fused mode-mix + inverse expand x,y ----------------
__global__ __launch_bounds__(256) void k_efmix_all(const float* __restrict__ Zxy_d,
                                                   const float* __restrict__ Zxy_s,
                                                   __half* __restrict__ Z6a,
                                                   __half* __restrict__ Z6b,
                                                   __half* __restrict__ Z6c, WArgs wa,
                                                   const float* __restrict__ twx_all,
                                                   Levels lv) {
  __shared__ float zm[1200];   // [jx*kn+jy][12]
  __shared__ float S1[3840];   // [x*kn+jy][12]
  __shared__ float tx[640];
  int lev = blockIdx.x / 432;
  int r = blockIdx.x % 432;
  int batch = r / 144;
  int rr = r % 144;
  int b = rr / 9, o = rr % 9;
  int n = lv.n[lev], kn = lv.kn[lev];
  int nm = kn * kn * 5;
  int tid = threadIdx.x;
  const float* twx = twx_all + lev * 640;
  const float* in = (batch == 1 ? Zxy_s : Zxy_d) + lv.zxy_off[lev] + (long)b * 9 * nm * 2;
  const float2* in2 = reinterpret_cast<const float2*>(in);
  __half* out = (batch == 0 ? Z6a : batch == 1 ? Z6b : Z6c) + lv.z6_off[lev] +
                ((long)(b * 9 + o)) * n * n * 10;
  for (int i = tid; i < kn * n * 2; i += 256) tx[i] = twx[i];
  __syncthreads();
  int l1 = (5 < n / 2 + 1) ? 5 : n / 2 + 1;
  for (int m = tid; m < nm; m += 256) {
    int kz = m % 5, jy = (m / 5) % kn, jx = m / (5 * kn);
    int kx = (kn < 10) ? jx : (jx < 5 ? jx : n - 10 + jx);
    int ky = (kn < 10) ? jy : (jy < 5 ? jy : n - 10 + jy);
    bool lx = kx < l1, hx = kx >= n - l1, ly = ky < l1, hy = ky >= n - l1;
    const float* wsel;
    int wx, wy;
    if (hx && hy) { wsel = wa.w[batch * 4 + 3]; wx = kx - (n - l1); wy = ky - (n - l1); }
    else if (lx && hy) { wsel = wa.w[batch * 4 + 2]; wx = kx; wy = ky - (n - l1); }
    else if (hx && ly) { wsel = wa.w[batch * 4 + 1]; wx = kx - (n - l1); wy = ky; }
    else { wsel = wa.w[batch * 4 + 0]; wx = kx; wy = ky; }
    const float* wp = wsel + o * 250 + wx * 50 + wy * 10 + kz * 2;
    float sr = 0.f, si = 0.f;
#pragma unroll
    for (int i = 0; i < 9; ++i) {
      float2 z = in2[i * nm + m];
      float2 w2 = *reinterpret_cast<const float2*>(&wp[i * 2250]);
      sr += z.x * w2.x - z.y * w2.y;
      si += z.x * w2.y + z.y * w2.x;
    }
    zm[(jx * kn + jy) * 12 + 2 * kz] = sr;
    zm[(jx * kn + jy) * 12 + 2 * kz + 1] = si;
  }
  __syncthreads();
  int t1n = n * kn;
  for (int task = tid; task < t1n; task += 256) {
    int jy = task % kn, x = task / kn;
    float acc[10];
#pragma unroll
    for (int j = 0; j < 10; ++j) acc[j] = 0.f;
    for (int jx = 0; jx < kn; ++jx) {
      const float* zr = &zm[(jx * kn + jy) * 12];
      float2 cs2 = *reinterpret_cast<const float2*>(&tx[2 * (jx * n + x)]);
#pragma unroll
      for (int kz = 0; kz < 5; ++kz) {
        float zx = zr[2 * kz], zy = zr[2 * kz + 1];
        acc[2 * kz] += zx * cs2.x - zy * cs2.y;
        acc[2 * kz + 1] += zx * cs2.y + zy * cs2.x;
      }
    }
    float* s1 = &S1[(x * kn + jy) * 12];
#pragma unroll
    for (int j = 0; j < 10; ++j) s1[j] = acc[j];
  }
  __syncthreads();
  int t2n = n * n;
  for (int task = tid; task < t2n; task += 256) {
    int y = task % n, x = task / n;
    float acc[10];
#pragma unroll
    for (int j = 0; j < 10; ++j) acc[j] = 0.f;
    for (int jy = 0; jy < kn; ++jy) {
      const float* zr = &S1[(x * kn + jy) * 12];
      float2 cs2 = *reinterpret_cast<const float2*>(&tx[2 * (jy * n + y)]);
#pragma unroll
      for (int kz = 0; kz < 5; ++kz) {
        float zx = zr[2 * kz], zy = zr[2 * kz + 1];
        acc[2 * kz] += zx * cs2.x - zy * cs2.y;
        acc[2 * kz + 1] += zx * cs2.y + zy * cs2.x;
      }
    }
    __half* op = out + (long)(x * n + y) * 10;
#pragma unroll
    for (int kz = 0; kz < 5; ++kz)
      *reinterpret_cast<__half2*>(op + 2 * kz) = __floats2half2_rn(acc[2 * kz], acc[2 * kz + 1]);
  }
}

// ---------------- levels 1-5 inverse-t(c2r) + ReLU + lo conv ----------------
__global__ __launch_bounds__(256) void k_gh3_all(const __half* __restrict__ Z6a,
                                                 const __half* __restrict__ Z6b,
                                                 const __half* __restrict__ Z6c,
                                                 const float* __restrict__ a_low,
                                                 const float* __restrict__ a_lob,
                                                 const float* __restrict__ b_low,
                                                 const float* __restrict__ b_lob,
                                                 const float* __restrict__ c_low,
                                                 const float* __restrict__ c_lob,
                                                 __half* __restrict__ Ud,
                                                 __half* __restrict__ Us,
                                                 const float* __restrict__ twt, Levels lv) {
  __shared__ float tw[640];
  __shared__ float zz[3][4][90];
  int tid = threadIdx.x;
  for (int i = tid; i < 640; i += 256) tw[i] = twt[i];
  int lev = 1;
  while (lev < 5 && (int)blockIdx.x >= lv.gstart[lev + 1]) ++lev;
  int n = lv.n[lev];
  float scale = lv.scale[lev];
  long pos0 = (long)(blockIdx.x - lv.gstart[lev]) * 4;
  long total = (long)NB * n * n;
  const __half* zbuf[3] = {Z6a + lv.z6_off[lev], Z6b + lv.z6_off[lev], Z6c + lv.z6_off[lev]};
  for (int i = tid; i < 540; i += 256) {
    int bi = i / 180;
    int rr2 = i % 180;
    int p = rr2 / 45;
    int q = rr2 % 45;
    int ch = q / 5, kz = q % 5;
    long pos = pos0 + p;
    if (pos < total) {
      int b = (int)(pos / (n * n));
      int rem = (int)(pos % (n * n));
      const __half2* src = reinterpret_cast<const __half2*>(
          zbuf[bi] + ((long)(b * 9 + ch) * n * n + rem) * 10 + 2 * kz);
      float2 f = __half22float2(*src);
      *reinterpret_cast<float2*>(&zz[bi][p][ch * 10 + 2 * kz]) = f;
    }
  }
  __syncthreads();
  int p = tid / 64, t = tid & 63;
  long pos = pos0 + p;
  if (pos >= total) return;
  int b = (int)(pos / (n * n));
  int rem = (int)(pos % (n * n));
  float tc[4], tsn[4];
#pragma unroll
  for (int k = 1; k < 5; ++k) {
    float2 cs2 = *reinterpret_cast<const float2*>(&tw[2 * (k * 64 + t)]);
    tc[k - 1] = cs2.x;
    tsn[k - 1] = cs2.y;
  }
  float rva[9], rvb[9], rvc[9];
#pragma unroll
  for (int i = 0; i < 9; ++i) {
    const float* za = &zz[0][p][i * 10];
    const float* zb = &zz[1][p][i * 10];
    const float* zc = &zz[2][p][i * 10];
    float va = za[0], vb = zb[0], vc = zc[0];
#pragma unroll
    for (int k = 1; k < 5; ++k) {
      float2 za2 = *reinterpret_cast<const float2*>(&za[2 * k]);
      float2 zb2 = *reinterpret_cast<const float2*>(&zb[2 * k]);
      float2 zc2 = *reinterpret_cast<const float2*>(&zc[2 * k]);
      va += 2.f * (za2.x * tc[k - 1] - za2.y * tsn[k - 1]);
      vb += 2.f * (zb2.x * tc[k - 1] - zb2.y * tsn[k - 1]);
      vc += 2.f * (zc2.x * tc[k - 1] - zc2.y * tsn[k - 1]);
    }
    rva[i] = fmaxf(va * scale, 0.f);
    rvb[i] = fmaxf(vb * scale, 0.f);
    rvc[i] = fmaxf(vc * scale, 0.f);
  }
  long cs = (long)n * n * 64;
  long ob = (long)b * 9 * cs + (long)rem * 64 + t;
  __half* ud = Ud + lv.u_off[lev];
  __half* us = Us + lv.u_off[lev];
#pragma unroll
  for (int o = 0; o < 9; ++o) {
    float du = a_lob[o] + b_lob[o];
    float usv = c_lob[o];
#pragma unroll
    for (int i = 0; i < 9; ++i) {
      du += a_low[o * 9 + i] * rva[i] + b_low[o * 9 + i] * rvb[i];
      usv += c_low[o * 9 + i] * rvc[i];
    }
    ud[ob + o * cs] = __float2half(du);
    us[ob + o * cs] = __float2half(usv);
  }
}

// ---------------- single-pos recon step helper (o split across 4 warps) ----------------
__device__ inline void step1pos_par(const float* __restrict__ in, float* __restrict__ outp,
                                    const __half* __restrict__ us, const __half* __restrict__ ud,
                                    long chs, const float* __restrict__ rc, int t, int p) {
  float cat[18];
#pragma unroll
  for (int i = 0; i < 9; ++i) cat[i] = in[i * 64 + t] + __half2float(us[chs * i + t]);
#pragma unroll
  for (int i = 0; i < 9; ++i) cat[9 + i] = __half2float(ud[chs * i + t]);
  for (int o = p; o < 9; o += 4) {
    float s = 0.f;
#pragma unroll
    for (int i = 0; i < 18; ++i) s += cat[i] * rc[i * 9 + o];
    outp[o * 64 + t] = s;
  }
}

// ---------------- recon part A: t0 + levels 5..2 -> G2 [b][9][16x16][64] fp32 ----------
__global__ __launch_bounds__(256) void k_recon_a(
    const __half* __restrict__ s5, const float* __restrict__ t0w,
    const float* __restrict__ t0b, const __half* __restrict__ Ud,
    const __half* __restrict__ Us, const float* __restrict__ rcee,
    const float* __restrict__ rceo, const float* __restrict__ roe_,
    const float* __restrict__ roo_, float* __restrict__ G2, Levels lv) {
  __shared__ float A[576];
  __shared__ float Bq[576];
  int tid = threadIdx.x;
  int b = blockIdx.x >> 6;
  int T = blockIdx.x & 63;
  int tx = T >> 3, ty = T & 7;
  const float* rcw[4] = {rcee, rceo, roe_, roo_};
  int pg = tid >> 6, t64 = tid & 63;

  {  // t0
    float v[9];
#pragma unroll
    for (int i = 0; i < 9; ++i) v[i] = __half2float(s5[((long)b * 9 + i) * 64 + t64]);
    for (int o = pg; o < 9; o += 4) {
      float s = t0b[o];
#pragma unroll
      for (int i = 0; i < 9; ++i) s += t0w[o * 9 + i] * v[i];
      A[o * 64 + t64] = s;
    }
  }
  __syncthreads();
  {  // step 5
    int sel = ((tx >> 2) & 1) * 2 + ((ty >> 2) & 1);
    long base = lv.u_off[5] + (long)b * 9 * 64;
    step1pos_par(A, Bq, Us + base, Ud + base, 64, rcw[sel], t64, pg);
  }
  __syncthreads();
  {  // step 4
    int ip = (tx >> 2) * 2 + (ty >> 2);
    int sel = ((tx >> 1) & 1) * 2 + ((ty >> 1) & 1);
    long base = lv.u_off[4] + ((long)b * 9 * 4 + ip) * 64;
    step1pos_par(Bq, A, Us + base, Ud + base, 4 * 64, rcw[sel], t64, pg);
  }
  __syncthreads();
  {  // step 3
    int ip = (tx >> 1) * 4 + (ty >> 1);
    int sel = (tx & 1) * 2 + (ty & 1);
    long base = lv.u_off[3] + ((long)b * 9 * 16 + ip) * 64;
    step1pos_par(A, Bq, Us + base, Ud + base, 16 * 64, rcw[sel], t64, pg);
  }
  __syncthreads();
  {  // step 2: 4 quadrants -> global G2
    int ip = tx * 8 + ty;
    long base = lv.u_off[2] + ((long)b * 9 * 64 + ip) * 64;
    float cat[18];
#pragma unroll
    for (int i = 0; i < 9; ++i)
      cat[i] = Bq[i * 64 + t64] + __half2float(Us[base + (long)64 * 64 * i + t64]);
#pragma unroll
    for (int i = 0; i < 9; ++i) cat[9 + i] = __half2float(Ud[base + (long)64 * 64 * i + t64]);
    const float* rc = rcw[pg];
    int p2 = (2 * tx + (pg >> 1)) * 16 + (2 * ty + (pg & 1));
#pragma unroll
    for (int o = 0; o < 9; ++o) {
      float s = 0.f;
#pragma unroll
      for (int i = 0; i < 18; ++i) s += cat[i] * rc[i * 9 + o];
      G2[((long)(b * 9 + o) * 256 + p2) * 64 + t64] = s;
    }
  }
}

// ---------------- recon part B: levels 1+0 with fused gh3-lev0 ----------------
// block = (b, lev1-input pos p1 on 16x16). threads = 4 children (a,c) x 64 t.
__global__ __launch_bounds__(256) void k_recon_b(
    const float* __restrict__ G2, const __half* __restrict__ Ud,
    const __half* __restrict__ Us, const __half* __restrict__ Z6a,
    const __half* __restrict__ Z6b, const __half* __restrict__ Z6c,
    const float* __restrict__ a_low, const float* __restrict__ a_lob,
    const float* __restrict__ b_low, const float* __restrict__ b_lob,
    const float* __restrict__ c_low, const float* __restrict__ c_lob,
    const float* __restrict__ twt, float scale0, const float* __restrict__ rcee,
    const float* __restrict__ rceo, const float* __restrict__ roe_,
    const float* __restrict__ roo_, float* __restrict__ out, Levels lv) {
  __shared__ float tw[640];
  __shared__ float zz[3][4][90];
  int tid = threadIdx.x;
  int bid = blockIdx.x;
  int b = bid >> 8;
  int p1 = bid & 255;
  int g1x = p1 >> 4, g1y = p1 & 15;
  int grp = tid >> 6, t = tid & 63;
  int a = grp >> 1, c = grp & 1;
  const float* rcw[4] = {rcee, rceo, roe_, roo_};

  // stage twt + Z6 lev0 for the 4 children (z6_off[0] == 0)
  for (int i = tid; i < 640; i += 256) tw[i] = twt[i];
  {
    const __half* zb3[3] = {Z6a, Z6b, Z6c};
    for (int i = tid; i < 540; i += 256) {
      int bi = i / 180;
      int rr2 = i % 180;
      int g = rr2 / 45;
      int q = rr2 % 45;
      int ch = q / 5, kz = q % 5;
      int x0 = 2 * g1x + (g >> 1), y0 = 2 * g1y + (g & 1);
      int rem = x0 * 32 + y0;
      const __half2* src = reinterpret_cast<const __half2*>(
          zb3[bi] + ((long)(b * 9 + ch) * 1024 + rem) * 10 + 2 * kz);
      float2 f = __half22float2(*src);
      *reinterpret_cast<float2*>(&zz[bi][g][ch * 10 + 2 * kz]) = f;
    }
  }

  // step 1: lev1 recon at input pos p1, child (a,c)  (overlaps with staging)
  float out9[9];
  {
    const float* rc = rcw[a * 2 + c];
    long base1 = lv.u_off[1] + ((long)b * 9 * 256 + p1) * 64;
    float cat[18];
#pragma unroll
    for (int i = 0; i < 9; ++i)
      cat[i] = G2[((long)(b * 9 + i) * 256 + p1) * 64 + t] +
               __half2float(Us[base1 + (long)i * 256 * 64 + t]);
#pragma unroll
    for (int i = 0; i < 9; ++i)
      cat[9 + i] = __half2float(Ud[base1 + (long)i * 256 * 64 + t]);
#pragma unroll
    for (int o = 0; o < 9; ++o) {
      float s = 0.f;
#pragma unroll
      for (int i = 0; i < 18; ++i) s += cat[i] * rc[i * 9 + o];
      out9[o] = s;
    }
  }
  __syncthreads();
  // step 0 with fused gh3-lev0: compute Us/Ud lev0 in-register from staged Z6
  {
    float tc[4], tsn[4];
#pragma unroll
    for (int k = 1; k < 5; ++k) {
      float2 cs2 = *reinterpret_cast<const float2*>(&tw[2 * (k * 64 + t)]);
      tc[k - 1] = cs2.x;
      tsn[k - 1] = cs2.y;
    }
    float rva[9], rvb[9], rvc[9];
#pragma unroll
    for (int i = 0; i < 9; ++i) {
      const float* za = &zz[0][grp][i * 10];
      const float* zb = &zz[1][grp][i * 10];
      const float* zc = &zz[2][grp][i * 10];
      float va = za[0], vb = zb[0], vc = zc[0];
#pragma unroll
      for (int k = 1; k < 5; ++k) {
        float2 za2 = *reinterpret_cast<const float2*>(&za[2 * k]);
        float2 zb2 = *reinterpret_cast<const float2*>(&zb[2 * k]);
        float2 zc2 = *reinterpret_cast<const float2*>(&zc[2 * k]);
        va += 2.f * (za2.x * tc[k - 1] - za2.y * tsn[k - 1]);
        vb += 2.f * (zb2.x * tc[k - 1] - zb2.y * tsn[k - 1]);
        vc += 2.f * (zc2.x * tc[k - 1] - zc2.y * tsn[k - 1]);
      }
      rva[i] = fmaxf(va * scale0, 0.f);
      rvb[i] = fmaxf(vb * scale0, 0.f);
      rvc[i] = fmaxf(vc * scale0, 0.f);
    }
    float cat[18];
#pragma unroll
    for (int o = 0; o < 9; ++o) {
      float du = a_lob[o] + b_lob[o];
      float usv = c_lob[o];
#pragma unroll
      for (int i = 0; i < 9; ++i) {
        du += a_low[o * 9 + i] * rva[i] + b_low[o * 9 + i] * rvb[i];
        usv += c_low[o * 9 + i] * rvc[i];
      }
      cat[o] = out9[o] + usv;
      cat[9 + o] = du;
    }
    int x0 = 2 * g1x + a, y0 = 2 * g1y + c;
#pragma unroll
    for (int rx = 0; rx < 2; ++rx)
#pragma unroll
      for (int ry = 0; ry < 2; ++ry) {
        const float* rc = rcw[rx * 2 + ry];
        int X = 2 * x0 + rx, Y = 2 * y0 + ry;
#pragma unroll
        for (int o = 0; o < 9; ++o) {
          float s = 0.f;
#pragma unroll
          for (int i = 0; i < 18; ++i) s += cat[i] * rc[i * 9 + o];
          out[((((long)b * 9 + o) * 64 + X) * 64 + Y) * 64 + t] = s;
        }
      }
  }
}

extern "C" void kernel_launch(void* const* d_in, const int* in_sizes, int n_in, void* d_out,
                              int out_size, void* d_ws, size_t ws_size, hipStream_t stream) {
  (void)in_sizes; (void)n_in; (void)out_size; (void)ws_size;
  const float* x = (const float*)d_in[0];
  const float* aw[4] = {(const float*)d_in[1], (const float*)d_in[2], (const float*)d_in[3],
                        (const float*)d_in[4]};
  const float* a_low = (const float*)d_in[5];
  const float* a_lob = (const float*)d_in[6];
  const float* bw[4] = {(const float*)d_in[7], (const float*)d_in[8], (const float*)d_in[9],
                        (const float*)d_in[10]};
  const float* b_low = (const float*)d_in[11];
  const float* b_lob = (const float*)d_in[12];
  const float* cw[4] = {(const float*)d_in[13], (const float*)d_in[14], (const float*)d_in[15],
                        (const float*)d_in[16]};
  const float* c_low = (const float*)d_in[17];
  const float* c_lob = (const float*)d_in[18];
  const float* t0w = (const float*)d_in[19];
  const float* t0b = (const float*)d_in[20];
  const float* ecs = (const float*)d_in[21];
  const float* ecd = (const float*)d_in[22];
  const float* rcee = (const float*)d_in[23];
  const float* rceo = (const float*)d_in[24];
  const float* rcoe = (const float*)d_in[25];
  const float* rcoo = (const float*)d_in[26];

  Levels lv;
  {
    int zt = 0, zxy = 0;
    static const int uoff[6] = {0, 9437184, 11796480, 12386304, 12533760, 12570624};
    for (int lev = 0; lev < 6; ++lev) {
      int n = 32 >> lev;
      int kn = n < 10 ? n : 10;
      lv.n[lev] = n;
      lv.kn[lev] = kn;
      lv.zt_off[lev] = zt;
      lv.zxy_off[lev] = zxy;
      lv.z6_off[lev] = zt;
      lv.u_off[lev] = uoff[lev];
      lv.scale[lev] = 1.f / sqrtf((float)(n * n * 64));
      zt += NB * 9 * n * n * 10;
      zxy += NB * 9 * kn * kn * 10;
    }
    // gh3 grid over levels 1..5 only
    int gh = 0;
    lv.gstart[0] = 0;
    for (int lev = 1; lev < 6; ++lev) {
      lv.gstart[lev] = gh;
      gh += (NB * (32 >> lev) * (32 >> lev) + 3) / 4;
    }
    lv.gstart[6] = gh;
  }

  char* base = (char*)d_ws;
  size_t ob = 0;
  auto allocF = [&](size_t ne) { float* p = (float*)(base + ob); ob += ne * 4; return p; };
  auto allocH = [&](size_t ne) {
    __half* p = (__half*)(base + ob);
    ob += ((ne + 1) & ~(size_t)1) * 2;
    return p;
  };
  float* twt = allocF(640);
  float* twx = allocF(3840);
  float* Zt_d = allocF(1965600);
  float* Zt_s = allocF(1965600);
  float* Zxy_d = allocF(410400);
  float* Zxy_s = allocF(410400);
  float* G2 = allocF(2359296);
  __half* s_a = allocH(9437184);
  __half* s_b = allocH(9437184);
  __half* Z6a = allocH(1965600);
  __half* Z6b = allocH(1965600);
  __half* Z6c = allocH(1965600);
  __half* Ud = allocH(12579840);
  __half* Us = allocH(12579840);

  k_init<<<1, 256, 0, stream>>>(twt, twx);

  for (int lev = 0; lev < 6; ++lev) {
    int n = 32 >> lev;
    int nblk = (NB * n * n + 3) / 4;
    __half* s_cur = (lev & 1) ? s_b : s_a;
    float* ztd = Zt_d + lv.zt_off[lev];
    float* zts = Zt_s + lv.zt_off[lev];
    if (lev == 0)
      k_wavdft<float><<<nblk, 256, 0, stream>>>(x, ecd, ecs, s_cur, ztd, zts, twt, n,
                                                lv.scale[lev]);
    else
      k_wavdft<__half><<<nblk, 256, 0, stream>>>((lev & 1) ? s_a : s_b, ecd, ecs, s_cur, ztd,
                                                 zts, twt, n, lv.scale[lev]);
  }

  k_bc_all<<<6 * 288, 256, 0, stream>>>(Zt_d, Zt_s, Zxy_d, Zxy_s, twx, lv);
  WArgs wa;
  for (int j = 0; j < 4; ++j) { wa.w[j] = aw[j]; wa.w[4 + j] = bw[j]; wa.w[8 + j] = cw[j]; }
  k_efmix_all<<<6 * 432, 256, 0, stream>>>(Zxy_d, Zxy_s, Z6a, Z6b, Z6c, wa, twx, lv);
  k_gh3_all<<<lv.gstart[6], 256, 0, stream>>>(Z6a, Z6b, Z6c, a_low, a_lob, b_low, b_lob, c_low,
                                              c_lob, Ud, Us, twt, lv);

  k_recon_a<<<NB * 64, 256, 0, stream>>>(s_b, t0w, t0b, Ud, Us, rcee, rceo, rcoe, rcoo, G2,
                                         lv);
  k_recon_b<<<NB * 256, 256, 0, stream>>>(G2, Ud, Us, Z6a, Z6b, Z6c, a_low, a_lob, b_low,
                                          b_lob, c_low, c_lob, twt, lv.scale[0], rcee, rceo,
                                          rcoe, rcoo, (float*)d_out, lv);
}

// Round 17
// 250.492 us; speedup vs baseline: 1.4876x; 1.0130x over previous
//
#include <hip/hip_runtime.h>
#include <hip/hip_fp16.h>
#include <math.h>

#define NB 16
#define PI2 6.28318530717958647692f

struct Levels {
  int n[6], kn[6];
  int zt_off[6];   // float elements
  int zxy_off[6];  // float elements
  int z6_off[6];   // half elements
  int u_off[6];    // half elements
  int gstart[7];
  float scale[6];
};
struct WArgs {
  const float* w[12];
};

// ---------------- twiddle tables ----------------
__global__ __launch_bounds__(256) void k_init(float* __restrict__ twt, float* __restrict__ twx) {
  int tid = threadIdx.x;
  for (int i = tid; i < 5 * 64; i += 256) {
    int k = i >> 6, t = i & 63;
    float ang = (float)((k * t) & 63) * (PI2 / 64.f);
    float s, c;
    sincosf(ang, &s, &c);
    twt[2 * i] = c;
    twt[2 * i + 1] = s;
  }
  for (int lev = 0; lev < 6; ++lev) {
    int n = 32 >> lev;
    int kn = n < 10 ? n : 10;
    float* tx = twx + lev * 640;
    for (int i = tid; i < kn * n; i += 256) {
      int j = i / n, m = i % n;
      int k = (kn < 10) ? j : (j < 5 ? j : n - 10 + j);
      float ang = (float)((k * m) % n) * (PI2 / (float)n);
      float s, c;
      sincosf(ang, &s, &c);
      tx[2 * i] = c;
      tx[2 * i + 1] = s;
    }
  }
}

// ---------------- fused wavelet analysis + forward t-DFT ----------------
// V holds one ds-set at a time (d first, then s from registers): LDS 45->35.6 KB
template <typename T>
__global__ __launch_bounds__(256) void k_wavdft(const T* __restrict__ xin,
                                                const float* __restrict__ ecd,
                                                const float* __restrict__ ecs,
                                                __half* __restrict__ sout,
                                                float* __restrict__ Zd, float* __restrict__ Zs,
                                                const float* __restrict__ twt, int n,
                                                float scale) {
  __shared__ float V[36 * 66];     // (p*9 + ch)*66 + t  (one ds-set)
  __shared__ float Vp[36 * 164];   // [row(p*9+ch)][10][16] padded: stride 164
  __shared__ float tw[640];
  int tid = threadIdx.x;
  for (int i = tid; i < 640; i += 256) tw[i] = twt[i];
  long pos0 = (long)blockIdx.x * 4;
  long total = (long)NB * n * n;
  long nn = (long)n * n;
  int p = tid >> 6, t = tid & 63;
  long pos = pos0 + p;
  bool active = pos < total;
  float sacc[9];
  if (active) {
    int b = (int)(pos / nn);
    int rem = (int)(pos % nn);
    int xp = rem / n, yp = rem % n;
    int n2 = 2 * n;
    const T* xb = xin + (long)b * 9 * n2 * n2 * 64;
    float dacc[9];
#pragma unroll
    for (int o = 0; o < 9; ++o) { dacc[o] = 0.f; sacc[o] = 0.f; }
#pragma unroll
    for (int q = 0; q < 4; ++q) {
      int X = 2 * xp + (q >> 1), Y = 2 * yp + (q & 1);
      const T* xq = xb + ((long)X * n2 + Y) * 64 + t;
#pragma unroll
      for (int i = 0; i < 9; ++i) {
        float v = (float)xq[(long)i * n2 * n2 * 64];
#pragma unroll
        for (int o = 0; o < 9; ++o) {
          dacc[o] += v * ecd[(q * 9 + i) * 9 + o];
          sacc[o] += v * ecs[(q * 9 + i) * 9 + o];
        }
      }
    }
    long cs = nn * 64;
    __half* sp = sout + (long)b * 9 * cs + (long)rem * 64 + t;
#pragma unroll
    for (int o = 0; o < 9; ++o) {
      sp[o * cs] = __float2half(sacc[o]);
      V[(p * 9 + o) * 66 + t] = dacc[o];
    }
  }
  __syncthreads();
  int tq = tid & 15;
  float tc[5][4], tsn[5][4];
#pragma unroll
  for (int k = 0; k < 5; ++k)
#pragma unroll
    for (int j = 0; j < 4; ++j) {
      tc[k][j] = tw[2 * (k * 64 + tq * 4 + j)];
      tsn[k][j] = tw[2 * (k * 64 + tq * 4 + j) + 1];
    }
#pragma unroll
  for (int ds = 0; ds < 2; ++ds) {
    // partial products: 36 rows x 16 t-quads
    for (int slot = tid; slot < 576; slot += 256) {
      int row = slot >> 4;  // p*9 + ch
      const float* vr = &V[row * 66 + tq * 4];
      float v0 = vr[0], v1 = vr[1], v2 = vr[2], v3 = vr[3];
      float* vp = &Vp[row * 164 + tq];
#pragma unroll
      for (int k = 0; k < 5; ++k) {
        float pr = v0 * tc[k][0] + v1 * tc[k][1] + v2 * tc[k][2] + v3 * tc[k][3];
        float pi = -(v0 * tsn[k][0] + v1 * tsn[k][1] + v2 * tsn[k][2] + v3 * tsn[k][3]);
        vp[(2 * k) * 16] = pr;
        vp[(2 * k + 1) * 16] = pi;
      }
    }
    __syncthreads();
    // reduce: 360 tasks (row, j)
    for (int task = tid; task < 360; task += 256) {
      int row = task / 10, j = task % 10;
      const float* vp = &Vp[row * 164 + j * 16];
      float4 a = *reinterpret_cast<const float4*>(vp);
      float4 b4 = *reinterpret_cast<const float4*>(vp + 4);
      float4 c4 = *reinterpret_cast<const float4*>(vp + 8);
      float4 d4 = *reinterpret_cast<const float4*>(vp + 12);
      float s = ((a.x + a.y) + (a.z + a.w)) + ((b4.x + b4.y) + (b4.z + b4.w)) +
                ((c4.x + c4.y) + (c4.z + c4.w)) + ((d4.x + d4.y) + (d4.z + d4.w));
      int pp = row / 9, ch = row % 9;
      long pos2 = pos0 + pp;
      if (pos2 < total) {
        int b = (int)(pos2 / nn);
        int rem = (int)(pos2 % nn);
        float* o = (ds ? Zs : Zd) + ((long)(b * 9 + ch) * nn + rem) * 10 + j;
        o[0] = s * scale;
      }
    }
    __syncthreads();
    if (ds == 0) {
      // overwrite V with s-set from registers
      if (active) {
#pragma unroll
        for (int o = 0; o < 9; ++o) V[(p * 9 + o) * 66 + t] = sacc[o];
      }
      __syncthreads();
    }
  }
}

// ---------------- all-level forward y-DFT then x-DFT (padded kz-12 layout) -------------
__global__ __launch_bounds__(256) void k_bc_all(const float* __restrict__ Zt_d,
                                                const float* __restrict__ Zt_s,
                                                float* __restrict__ Zxy_d,
                                                float* __restrict__ Zxy_s,
                                                const float* __restrict__ twx_all, Levels lv) {
  __shared__ float S1[3840];  // [x*kn+jy][12]
  __shared__ float tx[640];
  int lev = blockIdx.x / 288;
  int r = blockIdx.x % 288;
  int ds = r / 144, bc = r % 144;
  int n = lv.n[lev], kn = lv.kn[lev];
  int tid = threadIdx.x;
  const float* twx = twx_all + lev * 640;
  for (int i = tid; i < kn * n * 2; i += 256) tx[i] = twx[i];
  __syncthreads();
  const float* in = (ds ? Zt_s : Zt_d) + lv.zt_off[lev] + (long)bc * n * n * 10;
  float* out = (ds ? Zxy_s : Zxy_d) + lv.zxy_off[lev] + (long)bc * kn * kn * 10;
  int t1n = n * kn;
  for (int task = tid; task < t1n; task += 256) {
    int jy = task % kn, x = task / kn;
    float acc[10];
#pragma unroll
    for (int j = 0; j < 10; ++j) acc[j] = 0.f;
    const float2* row2 = reinterpret_cast<const float2*>(in + (long)x * n * 10);
    for (int y = 0; y < n; ++y) {
      float2 cs2 = *reinterpret_cast<const float2*>(&tx[2 * (jy * n + y)]);
#pragma unroll
      for (int kz = 0; kz < 5; ++kz) {
        float2 z = row2[y * 5 + kz];
        acc[2 * kz] += z.x * cs2.x + z.y * cs2.y;
        acc[2 * kz + 1] += z.y * cs2.x - z.x * cs2.y;
      }
    }
    float* s1 = &S1[(x * kn + jy) * 12];
#pragma unroll
    for (int j = 0; j < 10; ++j) s1[j] = acc[j];
  }
  __syncthreads();
  int t2n = kn * kn;
  for (int task = tid; task < t2n; task += 256) {
    int jy = task % kn, jx = task / kn;
    float acc[10];
#pragma unroll
    for (int j = 0; j < 10; ++j) acc[j] = 0.f;
    for (int x = 0; x < n; ++x) {
      const float* zr = &S1[(x * kn + jy) * 12];
      float2 cs2 = *reinterpret_cast<const float2*>(&tx[2 * (jx * n + x)]);
#pragma unroll
      for (int kz = 0; kz < 5; ++kz) {
        float zx = zr[2 * kz], zy = zr[2 * kz + 1];
        acc[2 * kz] += zx * cs2.x + zy * cs2.y;
        acc[2 * kz + 1] += zy * cs2.x - zx * cs2.y;
      }
    }
    float* o = out + (jx * kn + jy) * 10;
#pragma unroll
    for (int j = 0; j < 10; ++j) o[j] = acc[j];
  }
}

// ---------------- all-level fused mode-mix + inverse expand x,y ----------------
__global__ __launch_bounds__(256) void k_efmix_all(const float* __restrict__ Zxy_d,
                                                   const float* __restrict__ Zxy_s,
                                                   __half* __restrict__ Z6a,
                                                   __half* __restrict__ Z6b,
                                                   __half* __restrict__ Z6c, WArgs wa,
                                                   const float* __restrict__ twx_all,
                                                   Levels lv) {
  __shared__ float zm[1200];   // [jx*kn+jy][12]
  __shared__ float S1[3840];   // [x*kn+jy][12]
  __shared__ float tx[640];
  int lev = blockIdx.x / 432;
  int r = blockIdx.x % 432;
  int batch = r / 144;
  int rr = r % 144;
  int b = rr / 9, o = rr % 9;
  int n = lv.n[lev], kn = lv.kn[lev];
  int nm = kn * kn * 5;
  int tid = threadIdx.x;
  const float* twx = twx_all + lev * 640;
  const float* in = (batch == 1 ? Zxy_s : Zxy_d) + lv.zxy_off[lev] + (long)b * 9 * nm * 2;
  const float2* in2 = reinterpret_cast<const float2*>(in);
  __half* out = (batch == 0 ? Z6a : batch == 1 ? Z6b : Z6c) + lv.z6_off[lev] +
                ((long)(b * 9 + o)) * n * n * 10;
  for (int i = tid; i < kn * n * 2; i += 256) tx[i] = twx[i];
  __syncthreads();
  int l1 = (5 < n / 2 + 1) ? 5 : n / 2 + 1;
  for (int m = tid; m < nm; m += 256) {
    int kz = m % 5, jy = (m / 5) % kn, jx = m / (5 * kn);
    int kx = (kn < 10) ? jx : (jx < 5 ? jx : n - 10 + jx);
    int ky = (kn < 10) ? jy : (jy < 5 ? jy : n - 10 + jy);
    bool lx = kx < l1, hx = kx >= n - l1, ly = ky < l1, hy = ky >= n - l1;
    const float* wsel;
    int wx, wy;
    if (hx && hy) { wsel = wa.w[batch * 4 + 3]; wx = kx - (n - l1); wy = ky - (n - l1); }
    else if (lx && hy) { wsel = wa.w[batch * 4 + 2]; wx = kx; wy = ky - (n - l1); }
    else if (hx && ly) { wsel = wa.w[batch * 4 + 1]; wx = kx - (n - l1); wy = ky; }
    else { wsel = wa.w[batch * 4 + 0]; wx = kx; wy = ky; }
    const float* wp = wsel + o * 250 + wx * 50 + wy * 10 + kz * 2;
    float sr = 0.f, si = 0.f;
#pragma unroll
    for (int i = 0; i < 9; ++i) {
      float2 z = in2[i * nm + m];
      float2 w2 = *reinterpret_cast<const float2*>(&wp[i * 2250]);
      sr += z.x * w2.x - z.y * w2.y;
      si += z.x * w2.y + z.y * w2.x;
    }
    zm[(jx * kn + jy) * 12 + 2 * kz] = sr;
    zm[(jx * kn + jy) * 12 + 2 * kz + 1] = si;
  }
  __syncthreads();
  int t1n = n * kn;
  for (int task = tid; task < t1n; task += 256) {
    int jy = task % kn, x = task / kn;
    float acc[10];
#pragma unroll
    for (int j = 0; j < 10; ++j) acc[j] = 0.f;
    for (int jx = 0; jx < kn; ++jx) {
      const float* zr = &zm[(jx * kn + jy) * 12];
      float2 cs2 = *reinterpret_cast<const float2*>(&tx[2 * (jx * n + x)]);
#pragma unroll
      for (int kz = 0; kz < 5; ++kz) {
        float zx = zr[2 * kz], zy = zr[2 * kz + 1];
        acc[2 * kz] += zx * cs2.x - zy * cs2.y;
        acc[2 * kz + 1] += zx * cs2.y + zy * cs2.x;
      }
    }
    float* s1 = &S1[(x * kn + jy) * 12];
#pragma unroll
    for (int j = 0; j < 10; ++j) s1[j] = acc[j];
  }
  __syncthreads();
  int t2n = n * n;
  for (int task = tid; task < t2n; task += 256) {
    int y = task % n, x = task / n;
    float acc[10];
#pragma unroll
    for (int j = 0; j < 10; ++j) acc[j] = 0.f;
    for (int jy = 0; jy < kn; ++jy) {
      const float* zr = &S1[(x * kn + jy) * 12];
      float2 cs2 = *reinterpret_cast<const float2*>(&tx[2 * (jy * n + y)]);
#pragma unroll
      for (int kz = 0; kz < 5; ++kz) {
        float zx = zr[2 * kz], zy = zr[2 * kz + 1];
        acc[2 * kz] += zx * cs2.x - zy * cs2.y;
        acc[2 * kz + 1] += zx * cs2.y + zy * cs2.x;
      }
    }
    __half* op = out + (long)(x * n + y) * 10;
#pragma unroll
    for (int kz = 0; kz < 5; ++kz)
      *reinterpret_cast<__half2*>(op + 2 * kz) = __floats2half2_rn(acc[2 * kz], acc[2 * kz + 1]);
  }
}

// ---------------- levels 1-5 inverse-t(c2r) + ReLU + lo conv ----------------
__global__ __launch_bounds__(256) void k_gh3_all(const __half* __restrict__ Z6a,
                                                 const __half* __restrict__ Z6b,
                                                 const __half* __restrict__ Z6c,
                                                 const float* __restrict__ a_low,
                                                 const float* __restrict__ a_lob,
                                                 const float* __restrict__ b_low,
                                                 const float* __restrict__ b_lob,
                                                 const float* __restrict__ c_low,
                                                 const float* __restrict__ c_lob,
                                                 __half* __restrict__ Ud,
                                                 __half* __restrict__ Us,
                                                 const float* __restrict__ twt, Levels lv) {
  __shared__ float tw[640];
  __shared__ float zz[3][4][90];
  int tid = threadIdx.x;
  for (int i = tid; i < 640; i += 256) tw[i] = twt[i];
  int lev = 1;
  while (lev < 5 && (int)blockIdx.x >= lv.gstart[lev + 1]) ++lev;
  int n = lv.n[lev];
  float scale = lv.scale[lev];
  long pos0 = (long)(blockIdx.x - lv.gstart[lev]) * 4;
  long total = (long)NB * n * n;
  const __half* zbuf[3] = {Z6a + lv.z6_off[lev], Z6b + lv.z6_off[lev], Z6c + lv.z6_off[lev]};
  for (int i = tid; i < 540; i += 256) {
    int bi = i / 180;
    int rr2 = i % 180;
    int p = rr2 / 45;
    int q = rr2 % 45;
    int ch = q / 5, kz = q % 5;
    long pos = pos0 + p;
    if (pos < total) {
      int b = (int)(pos / (n * n));
      int rem = (int)(pos % (n * n));
      const __half2* src = reinterpret_cast<const __half2*>(
          zbuf[bi] + ((long)(b * 9 + ch) * n * n + rem) * 10 + 2 * kz);
      float2 f = __half22float2(*src);
      *reinterpret_cast<float2*>(&zz[bi][p][ch * 10 + 2 * kz]) = f;
    }
  }
  __syncthreads();
  int p = tid / 64, t = tid & 63;
  long pos = pos0 + p;
  if (pos >= total) return;
  int b = (int)(pos / (n * n));
  int rem = (int)(pos % (n * n));
  float tc[4], tsn[4];
#pragma unroll
  for (int k = 1; k < 5; ++k) {
    float2 cs2 = *reinterpret_cast<const float2*>(&tw[2 * (k * 64 + t)]);
    tc[k - 1] = cs2.x;
    tsn[k - 1] = cs2.y;
  }
  float rva[9], rvb[9], rvc[9];
#pragma unroll
  for (int i = 0; i < 9; ++i) {
    const float* za = &zz[0][p][i * 10];
    const float* zb = &zz[1][p][i * 10];
    const float* zc = &zz[2][p][i * 10];
    float va = za[0], vb = zb[0], vc = zc[0];
#pragma unroll
    for (int k = 1; k < 5; ++k) {
      float2 za2 = *reinterpret_cast<const float2*>(&za[2 * k]);
      float2 zb2 = *reinterpret_cast<const float2*>(&zb[2 * k]);
      float2 zc2 = *reinterpret_cast<const float2*>(&zc[2 * k]);
      va += 2.f * (za2.x * tc[k - 1] - za2.y * tsn[k - 1]);
      vb += 2.f * (zb2.x * tc[k - 1] - zb2.y * tsn[k - 1]);
      vc += 2.f * (zc2.x * tc[k - 1] - zc2.y * tsn[k - 1]);
    }
    rva[i] = fmaxf(va * scale, 0.f);
    rvb[i] = fmaxf(vb * scale, 0.f);
    rvc[i] = fmaxf(vc * scale, 0.f);
  }
  long cs = (long)n * n * 64;
  long ob = (long)b * 9 * cs + (long)rem * 64 + t;
  __half* ud = Ud + lv.u_off[lev];
  __half* us = Us + lv.u_off[lev];
#pragma unroll
  for (int o = 0; o < 9; ++o) {
    float du = a_lob[o] + b_lob[o];
    float usv = c_lob[o];
#pragma unroll
    for (int i = 0; i < 9; ++i) {
      du += a_low[o * 9 + i] * rva[i] + b_low[o * 9 + i] * rvb[i];
      usv += c_low[o * 9 + i] * rvc[i];
    }
    ud[ob + o * cs] = __float2half(du);
    us[ob + o * cs] = __float2half(usv);
  }
}

// ---------------- single-pos recon step helper (o split across 4 warps) ----------------
__device__ inline void step1pos_par(const float* __restrict__ in, float* __restrict__ outp,
                                    const __half* __restrict__ us, const __half* __restrict__ ud,
                                    long chs, const float* __restrict__ rc, int t, int p) {
  float cat[18];
#pragma unroll
  for (int i = 0; i < 9; ++i) cat[i] = in[i * 64 + t] + __half2float(us[chs * i + t]);
#pragma unroll
  for (int i = 0; i < 9; ++i) cat[9 + i] = __half2float(ud[chs * i + t]);
  for (int o = p; o < 9; o += 4) {
    float s = 0.f;
#pragma unroll
    for (int i = 0; i < 18; ++i) s += cat[i] * rc[i * 9 + o];
    outp[o * 64 + t] = s;
  }
}

// ---------------- recon part A: t0 + levels 5..2 -> G2 [b][9][16x16][64] fp32 ----------
__global__ __launch_bounds__(256) void k_recon_a(
    const __half* __restrict__ s5, const float* __restrict__ t0w,
    const float* __restrict__ t0b, const __half* __restrict__ Ud,
    const __half* __restrict__ Us, const float* __restrict__ rcee,
    const float* __restrict__ rceo, const float* __restrict__ roe_,
    const float* __restrict__ roo_, float* __restrict__ G2, Levels lv) {
  __shared__ float A[576];
  __shared__ float Bq[576];
  int tid = threadIdx.x;
  int b = blockIdx.x >> 6;
  int T = blockIdx.x & 63;
  int tx = T >> 3, ty = T & 7;
  const float* rcw[4] = {rcee, rceo, roe_, roo_};
  int pg = tid >> 6, t64 = tid & 63;

  {  // t0
    float v[9];
#pragma unroll
    for (int i = 0; i < 9; ++i) v[i] = __half2float(s5[((long)b * 9 + i) * 64 + t64]);
    for (int o = pg; o < 9; o += 4) {
      float s = t0b[o];
#pragma unroll
      for (int i = 0; i < 9; ++i) s += t0w[o * 9 + i] * v[i];
      A[o * 64 + t64] = s;
    }
  }
  __syncthreads();
  {  // step 5
    int sel = ((tx >> 2) & 1) * 2 + ((ty >> 2) & 1);
    long base = lv.u_off[5] + (long)b * 9 * 64;
    step1pos_par(A, Bq, Us + base, Ud + base, 64, rcw[sel], t64, pg);
  }
  __syncthreads();
  {  // step 4
    int ip = (tx >> 2) * 2 + (ty >> 2);
    int sel = ((tx >> 1) & 1) * 2 + ((ty >> 1) & 1);
    long base = lv.u_off[4] + ((long)b * 9 * 4 + ip) * 64;
    step1pos_par(Bq, A, Us + base, Ud + base, 4 * 64, rcw[sel], t64, pg);
  }
  __syncthreads();
  {  // step 3
    int ip = (tx >> 1) * 4 + (ty >> 1);
    int sel = (tx & 1) * 2 + (ty & 1);
    long base = lv.u_off[3] + ((long)b * 9 * 16 + ip) * 64;
    step1pos_par(A, Bq, Us + base, Ud + base, 16 * 64, rcw[sel], t64, pg);
  }
  __syncthreads();
  {  // step 2: 4 quadrants -> global G2
    int ip = tx * 8 + ty;
    long base = lv.u_off[2] + ((long)b * 9 * 64 + ip) * 64;
    float cat[18];
#pragma unroll
    for (int i = 0; i < 9; ++i)
      cat[i] = Bq[i * 64 + t64] + __half2float(Us[base + (long)64 * 64 * i + t64]);
#pragma unroll
    for (int i = 0; i < 9; ++i) cat[9 + i] = __half2float(Ud[base + (long)64 * 64 * i + t64]);
    const float* rc = rcw[pg];
    int p2 = (2 * tx + (pg >> 1)) * 16 + (2 * ty + (pg & 1));
#pragma unroll
    for (int o = 0; o < 9; ++o) {
      float s = 0.f;
#pragma unroll
      for (int i = 0; i < 18; ++i) s += cat[i] * rc[i * 9 + o];
      G2[((long)(b * 9 + o) * 256 + p2) * 64 + t64] = s;
    }
  }
}

// ---------------- recon part B: levels 1+0 with fused gh3-lev0 ----------------
// block = (b, lev1-input pos p1 on 16x16). threads = 4 children (a,c) x 64 t.
__global__ __launch_bounds__(256) void k_recon_b(
    const float* __restrict__ G2, const __half* __restrict__ Ud,
    const __half* __restrict__ Us, const __half* __restrict__ Z6a,
    const __half* __restrict__ Z6b, const __half* __restrict__ Z6c,
    const float* __restrict__ a_low, const float* __restrict__ a_lob,
    const float* __restrict__ b_low, const float* __restrict__ b_lob,
    const float* __restrict__ c_low, const float* __restrict__ c_lob,
    const float* __restrict__ twt, float scale0, const float* __restrict__ rcee,
    const float* __restrict__ rceo, const float* __restrict__ roe_,
    const float* __restrict__ roo_, float* __restrict__ out, Levels lv) {
  __shared__ float tw[640];
  __shared__ float zz[3][4][90];
  int tid = threadIdx.x;
  int bid = blockIdx.x;
  int b = bid >> 8;
  int p1 = bid & 255;
  int g1x = p1 >> 4, g1y = p1 & 15;
  int grp = tid >> 6, t = tid & 63;
  int a = grp >> 1, c = grp & 1;
  const float* rcw[4] = {rcee, rceo, roe_, roo_};

  // stage twt + Z6 lev0 for the 4 children (z6_off[0] == 0)
  for (int i = tid; i < 640; i += 256) tw[i] = twt[i];
  {
    const __half* zb3[3] = {Z6a, Z6b, Z6c};
    for (int i = tid; i < 540; i += 256) {
      int bi = i / 180;
      int rr2 = i % 180;
      int g = rr2 / 45;
      int q = rr2 % 45;
      int ch = q / 5, kz = q % 5;
      int x0 = 2 * g1x + (g >> 1), y0 = 2 * g1y + (g & 1);
      int rem = x0 * 32 + y0;
      const __half2* src = reinterpret_cast<const __half2*>(
          zb3[bi] + ((long)(b * 9 + ch) * 1024 + rem) * 10 + 2 * kz);
      float2 f = __half22float2(*src);
      *reinterpret_cast<float2*>(&zz[bi][g][ch * 10 + 2 * kz]) = f;
    }
  }

  // step 1: lev1 recon at input pos p1, child (a,c)  (overlaps with staging)
  float out9[9];
  {
    const float* rc = rcw[a * 2 + c];
    long base1 = lv.u_off[1] + ((long)b * 9 * 256 + p1) * 64;
    float cat[18];
#pragma unroll
    for (int i = 0; i < 9; ++i)
      cat[i] = G2[((long)(b * 9 + i) * 256 + p1) * 64 + t] +
               __half2float(Us[base1 + (long)i * 256 * 64 + t]);
#pragma unroll
    for (int i = 0; i < 9; ++i)
      cat[9 + i] = __half2float(Ud[base1 + (long)i * 256 * 64 + t]);
#pragma unroll
    for (int o = 0; o < 9; ++o) {
      float s = 0.f;
#pragma unroll
      for (int i = 0; i < 18; ++i) s += cat[i] * rc[i * 9 + o];
      out9[o] = s;
    }
  }
  __syncthreads();
  // step 0 with fused gh3-lev0: compute Us/Ud lev0 in-register from staged Z6
  {
    float tc[4], tsn[4];
#pragma unroll
    for (int k = 1; k < 5; ++k) {
      float2 cs2 = *reinterpret_cast<const float2*>(&tw[2 * (k * 64 + t)]);
      tc[k - 1] = cs2.x;
      tsn[k - 1] = cs2.y;
    }
    float rva[9], rvb[9], rvc[9];
#pragma unroll
    for (int i = 0; i < 9; ++i) {
      const float* za = &zz[0][grp][i * 10];
      const float* zb = &zz[1][grp][i * 10];
      const float* zc = &zz[2][grp][i * 10];
      float va = za[0], vb = zb[0], vc = zc[0];
#pragma unroll
      for (int k = 1; k < 5; ++k) {
        float2 za2 = *reinterpret_cast<const float2*>(&za[2 * k]);
        float2 zb2 = *reinterpret_cast<const float2*>(&zb[2 * k]);
        float2 zc2 = *reinterpret_cast<const float2*>(&zc[2 * k]);
        va += 2.f * (za2.x * tc[k - 1] - za2.y * tsn[k - 1]);
        vb += 2.f * (zb2.x * tc[k - 1] - zb2.y * tsn[k - 1]);
        vc += 2.f * (zc2.x * tc[k - 1] - zc2.y * tsn[k - 1]);
      }
      rva[i] = fmaxf(va * scale0, 0.f);
      rvb[i] = fmaxf(vb * scale0, 0.f);
      rvc[i] = fmaxf(vc * scale0, 0.f);
    }
    float cat[18];
#pragma unroll
    for (int o = 0; o < 9; ++o) {
      float du = a_lob[o] + b_lob[o];
      float usv = c_lob[o];
#pragma unroll
      for (int i = 0; i < 9; ++i) {
        du += a_low[o * 9 + i] * rva[i] + b_low[o * 9 + i] * rvb[i];
        usv += c_low[o * 9 + i] * rvc[i];
      }
      cat[o] = out9[o] + usv;
      cat[9 + o] = du;
    }
    int x0 = 2 * g1x + a, y0 = 2 * g1y + c;
#pragma unroll
    for (int rx = 0; rx < 2; ++rx)
#pragma unroll
      for (int ry = 0; ry < 2; ++ry) {
        const float* rc = rcw[rx * 2 + ry];
        int X = 2 * x0 + rx, Y = 2 * y0 + ry;
#pragma unroll
        for (int o = 0; o < 9; ++o) {
          float s = 0.f;
#pragma unroll
          for (int i = 0; i < 18; ++i) s += cat[i] * rc[i * 9 + o];
          out[((((long)b * 9 + o) * 64 + X) * 64 + Y) * 64 + t] = s;
        }
      }
  }
}

extern "C" void kernel_launch(void* const* d_in, const int* in_sizes, int n_in, void* d_out,
                              int out_size, void* d_ws, size_t ws_size, hipStream_t stream) {
  (void)in_sizes; (void)n_in; (void)out_size; (void)ws_size;
  const float* x = (const float*)d_in[0];
  const float* aw[4] = {(const float*)d_in[1], (const float*)d_in[2], (const float*)d_in[3],
                        (const float*)d_in[4]};
  const float* a_low = (const float*)d_in[5];
  const float* a_lob = (const float*)d_in[6];
  const float* bw[4] = {(const float*)d_in[7], (const float*)d_in[8], (const float*)d_in[9],
                        (const float*)d_in[10]};
  const float* b_low = (const float*)d_in[11];
  const float* b_lob = (const float*)d_in[12];
  const float* cw[4] = {(const float*)d_in[13], (const float*)d_in[14], (const float*)d_in[15],
                        (const float*)d_in[16]};
  const float* c_low = (const float*)d_in[17];
  const float* c_lob = (const float*)d_in[18];
  const float* t0w = (const float*)d_in[19];
  const float* t0b = (const float*)d_in[20];
  const float* ecs = (const float*)d_in[21];
  const float* ecd = (const float*)d_in[22];
  const float* rcee = (const float*)d_in[23];
  const float* rceo = (const float*)d_in[24];
  const float* rcoe = (const float*)d_in[25];
  const float* rcoo = (const float*)d_in[26];

  Levels lv;
  {
    int zt = 0, zxy = 0;
    static const int uoff[6] = {0, 9437184, 11796480, 12386304, 12533760, 12570624};
    for (int lev = 0; lev < 6; ++lev) {
      int n = 32 >> lev;
      int kn = n < 10 ? n : 10;
      lv.n[lev] = n;
      lv.kn[lev] = kn;
      lv.zt_off[lev] = zt;
      lv.zxy_off[lev] = zxy;
      lv.z6_off[lev] = zt;
      lv.u_off[lev] = uoff[lev];
      lv.scale[lev] = 1.f / sqrtf((float)(n * n * 64));
      zt += NB * 9 * n * n * 10;
      zxy += NB * 9 * kn * kn * 10;
    }
    // gh3 grid over levels 1..5 only
    int gh = 0;
    lv.gstart[0] = 0;
    for (int lev = 1; lev < 6; ++lev) {
      lv.gstart[lev] = gh;
      gh += (NB * (32 >> lev) * (32 >> lev) + 3) / 4;
    }
    lv.gstart[6] = gh;
  }

  char* base = (char*)d_ws;
  size_t ob = 0;
  auto allocF = [&](size_t ne) { float* p = (float*)(base + ob); ob += ne * 4; return p; };
  auto allocH = [&](size_t ne) {
    __half* p = (__half*)(base + ob);
    ob += ((ne + 1) & ~(size_t)1) * 2;
    return p;
  };
  float* twt = allocF(640);
  float* twx = allocF(3840);
  float* Zt_d = allocF(1965600);
  float* Zt_s = allocF(1965600);
  float* Zxy_d = allocF(410400);
  float* Zxy_s = allocF(410400);
  float* G2 = allocF(2359296);
  __half* s_a = allocH(9437184);
  __half* s_b = allocH(9437184);
  __half* Z6a = allocH(1965600);
  __half* Z6b = allocH(1965600);
  __half* Z6c = allocH(1965600);
  __half* Ud = allocH(12579840);
  __half* Us = allocH(12579840);

  k_init<<<1, 256, 0, stream>>>(twt, twx);

  for (int lev = 0; lev < 6; ++lev) {
    int n = 32 >> lev;
    int nblk = (NB * n * n + 3) / 4;
    __half* s_cur = (lev & 1) ? s_b : s_a;
    float* ztd = Zt_d + lv.zt_off[lev];
    float* zts = Zt_s + lv.zt_off[lev];
    if (lev == 0)
      k_wavdft<float><<<nblk, 256, 0, stream>>>(x, ecd, ecs, s_cur, ztd, zts, twt, n,
                                                lv.scale[lev]);
    else
      k_wavdft<__half><<<nblk, 256, 0, stream>>>((lev & 1) ? s_a : s_b, ecd, ecs, s_cur, ztd,
                                                 zts, twt, n, lv.scale[lev]);
  }

  k_bc_all<<<6 * 288, 256, 0, stream>>>(Zt_d, Zt_s, Zxy_d, Zxy_s, twx, lv);
  WArgs wa;
  for (int j = 0; j < 4; ++j) { wa.w[j] = aw[j]; wa.w[4 + j] = bw[j]; wa.w[8 + j] = cw[j]; }
  k_efmix_all<<<6 * 432, 256, 0, stream>>>(Zxy_d, Zxy_s, Z6a, Z6b, Z6c, wa, twx, lv);
  k_gh3_all<<<lv.gstart[6], 256, 0, stream>>>(Z6a, Z6b, Z6c, a_low, a_lob, b_low, b_lob, c_low,
                                              c_lob, Ud, Us, twt, lv);

  k_recon_a<<<NB * 64, 256, 0, stream>>>(s_b, t0w, t0b, Ud, Us, rcee, rceo, rcoe, rcoo, G2,
                                         lv);
  k_recon_b<<<NB * 256, 256, 0, stream>>>(G2, Ud, Us, Z6a, Z6b, Z6c, a_low, a_lob, b_low,
                                          b_lob, c_low, c_lob, twt, lv.scale[0], rcee, rceo,
                                          rcoe, rcoo, (float*)d_out, lv);
}